// Round 9
// baseline (5577.929 us; speedup 1.0000x reference)
//
#include <hip/hip_runtime.h>
#include <stdint.h>

#define B_ 64
#define T_ 128
#define DIN_ 32
#define DOUT_ 64
#define HE_ 512
#define HD_ 1024
#define NPSI_ 1148928
#define PPS_ 100352   // per-sample non-Whh params (floats): bh[1024] Wih[32*1024] C[1024*64] D[32*32]

typedef short bf16x8 __attribute__((ext_vector_type(8)));
typedef float f32x4 __attribute__((ext_vector_type(4)));
typedef int   i32x4 __attribute__((ext_vector_type(4)));

__device__ __forceinline__ unsigned short f2b(float f){
  unsigned u = __float_as_uint(f);
  u += 0x7fffu + ((u>>16)&1u);      // round-to-nearest-even bf16
  return (unsigned short)(u>>16);
}
__device__ __forceinline__ float b2f(unsigned short s){
  return __uint_as_float(((unsigned)s)<<16);
}
__device__ __forceinline__ float sigm_(float x){
  float e = __expf(-x);
  return 1.f/(1.f+e);
}
__device__ __forceinline__ float tanh_(float x){
  float e = __expf(2.f*x);
  return 1.f - 2.f/(e+1.f);         // safe at +-inf
}
// async global->LDS: 64 lanes x 16 B = 1 KB; LDS dest wave-uniform, global
// src per-lane. Counts in vmcnt.
__device__ __forceinline__ void glds16(const void* g, void* l) {
  __builtin_amdgcn_global_load_lds(
      (const __attribute__((address_space(1))) unsigned int*)g,
      (__attribute__((address_space(3))) unsigned int*)l, 16, 0, 0);
}

// ---------------- prep: bf16 frag swizzles, gru int8 quant, h_dec init ------
__global__ __launch_bounds__(512) void k_prep(
    const float* __restrict__ enc_Whh, const float* __restrict__ enc_Wih,
    const float* __restrict__ gru_Whh, const float* __restrict__ state,
    unsigned short* __restrict__ encW_f, unsigned short* __restrict__ encI_f,
    signed char* __restrict__ gru_q, float* __restrict__ scales_g,
    unsigned short* __restrict__ h_dec)
{
  __shared__ unsigned gmax_s;
  __shared__ __align__(16) signed char gq[512];
  int blk = blockIdx.x, tid = threadIdx.x;
  if (blk < 1536) {                       // enc_Whh: gh = h @ Whh^T -> B[k][n]=Whh[n][k]
    int nt = blk >> 4, kt = blk & 15;
    int c = tid >> 5, k = tid & 31;
    float v = enc_Whh[(size_t)(nt*16 + c)*HE_ + kt*32 + k];
    int l = c + ((k>>3)<<4), jj = k & 7;
    encW_f[(size_t)(nt*16 + kt)*512 + l*8 + jj] = f2b(v);
  } else if (blk < 1728) {                // enc_Wih: B[k][n]=Wih[n][k]
    int f = blk - 1536; int nt = f >> 1, kt = f & 1;
    int c = tid >> 5, k = tid & 31;
    float v = enc_Wih[(size_t)(nt*16 + c)*DOUT_ + kt*32 + k];
    int l = c + ((k>>3)<<4), jj = k & 7;
    encI_f[(size_t)(nt*2 + kt)*512 + l*8 + jj] = f2b(v);
  } else if (blk < 5824) {                // gru_Whh -> int8 frags + per-tile scale
    int f = blk - 1728; int nt = f >> 5, kt = f & 31;
    int k = tid >> 4, c = tid & 15;
    float v = gru_Whh[(size_t)(kt*32 + k)*2048 + nt*16 + c];
    int l = c + ((k>>3)<<4), jj = k & 7;
    if (tid == 0) gmax_s = 0;
    __syncthreads();
    float av = fabsf(v);
    #pragma unroll
    for (int d = 1; d < 64; d <<= 1) av = fmaxf(av, __shfl_xor(av, d));
    if ((tid & 63) == 0) atomicMax(&gmax_s, __float_as_uint(av));
    __syncthreads();
    float m = __uint_as_float(gmax_s);
    float inv = (m > 0.f) ? (127.f/m) : 0.f;
    gq[l*8 + jj] = (signed char)(int)rintf(v*inv);
    __syncthreads();
    if (tid < 32)
      *(i32x4*)(gru_q + (size_t)(nt*32 + kt)*512 + tid*16) = *(const i32x4*)(&gq[tid*16]);
    if (tid == 0) scales_g[nt*32 + kt] = m;
  } else {                                // h_dec buf0 init from `state`
    int b = blk - 5824;
    h_dec[(size_t)b*HD_ + tid]       = f2b(state[(size_t)b*HD_ + tid]);
    h_dec[(size_t)b*HD_ + 512 + tid] = f2b(state[(size_t)b*HD_ + 512 + tid]);
  }
}

// ---------------- encoder: 16 groups x 32 blocks x 2 waves (K-split), 4 samples
__global__ __launch_bounds__(128) void k_encoder(
    const float* __restrict__ outputs, const float* __restrict__ bih, const float* __restrict__ bhh,
    const unsigned short* __restrict__ encW_f, const unsigned short* __restrict__ encI_f,
    unsigned short* __restrict__ h_buf, float* __restrict__ h_enc, unsigned int* __restrict__ bar)
{
  __shared__ __align__(16) unsigned short h_bf[16*520];   // rows 4-15 stay zero
  __shared__ __align__(16) unsigned short xa[16*72];
  __shared__ float part[64*16];                           // wave1 partial accs
  int tid = threadIdx.x, wv = tid >> 6, lane = tid & 63;
  int g = blockIdx.x >> 5, bg = blockIdx.x & 31;
  int c0 = bg*16, gs = g*4;
  for (int i = tid; i < 16*520; i += 128) h_bf[i] = 0;
  for (int i = tid; i < 16*72; i += 128) xa[i] = 0;
  int cl = c0 + (lane & 15);
  float br_b = bih[cl] + bhh[cl];
  float bz_b = bih[512+cl] + bhh[512+cl];
  float bin_b = bih[1024+cl];
  float bhn_b = bhh[1024+cl];
  float hreg[4] = {0.f,0.f,0.f,0.f};
  int nt_r = bg, nt_z = 32+bg, nt_n = 64+bg;
  __syncthreads();
  for (int t = 0; t < 128; ++t) {
    int rb = t & 1;
    if (t > 0) {
      if (tid == 0) {
        while (__hip_atomic_load(&bar[(g<<7)+(t-1)], __ATOMIC_ACQUIRE, __HIP_MEMORY_SCOPE_AGENT) < 32u)
          __builtin_amdgcn_s_sleep(2);
      }
      __syncthreads();
    }
    { // reload h (4 samples x 512 bf16) + x_t
      const unsigned short* src = h_buf + (size_t)rb*B_*HE_ + (size_t)gs*HE_;
      #pragma unroll
      for (int j = 0; j < 2; ++j) {
        int chunk = j*128 + tid;
        bf16x8 v = *(const bf16x8*)(src + chunk*8);
        int s = chunk >> 6, col = (chunk & 63) * 8;
        *(bf16x8*)(&h_bf[s*520 + col]) = v;
      }
      #pragma unroll
      for (int j = 0; j < 2; ++j) {
        int e = j*128 + tid;
        int s = e >> 6, d = e & 63;
        xa[s*72 + d] = f2b(outputs[((size_t)(gs+s)*T_ + t)*DOUT_ + d]);
      }
    }
    __syncthreads();
    f32x4 accr = {0,0,0,0}, accz = {0,0,0,0}, accn = {0,0,0,0}, accgi = {0,0,0,0};
    { // gi = x @ Wih^T, kt = wv
      bf16x8 a = *(const bf16x8*)(&xa[(lane&15)*72 + wv*32 + ((lane>>4)<<3)]);
      bf16x8 b0 = *(const bf16x8*)(encI_f + (size_t)(nt_r*2+wv)*512 + lane*8);
      bf16x8 b1 = *(const bf16x8*)(encI_f + (size_t)(nt_z*2+wv)*512 + lane*8);
      bf16x8 b2 = *(const bf16x8*)(encI_f + (size_t)(nt_n*2+wv)*512 + lane*8);
      accr  = __builtin_amdgcn_mfma_f32_16x16x32_bf16(a, b0, accr, 0,0,0);
      accz  = __builtin_amdgcn_mfma_f32_16x16x32_bf16(a, b1, accz, 0,0,0);
      accgi = __builtin_amdgcn_mfma_f32_16x16x32_bf16(a, b2, accgi, 0,0,0);
    }
    #pragma unroll
    for (int kk = 0; kk < 8; ++kk) {      // gh = h @ Whh^T, K-half per wave
      int kt = wv*8 + kk;
      bf16x8 a = *(const bf16x8*)(&h_bf[(lane&15)*520 + kt*32 + ((lane>>4)<<3)]);
      bf16x8 b0 = *(const bf16x8*)(encW_f + (size_t)(nt_r*16+kt)*512 + lane*8);
      bf16x8 b1 = *(const bf16x8*)(encW_f + (size_t)(nt_z*16+kt)*512 + lane*8);
      bf16x8 b2 = *(const bf16x8*)(encW_f + (size_t)(nt_n*16+kt)*512 + lane*8);
      accr = __builtin_amdgcn_mfma_f32_16x16x32_bf16(a, b0, accr, 0,0,0);
      accz = __builtin_amdgcn_mfma_f32_16x16x32_bf16(a, b1, accz, 0,0,0);
      accn = __builtin_amdgcn_mfma_f32_16x16x32_bf16(a, b2, accn, 0,0,0);
    }
    if (wv == 1) {
      #pragma unroll
      for (int i = 0; i < 4; ++i) {
        part[lane*16 + i]      = accr[i];
        part[lane*16 + 4 + i]  = accz[i];
        part[lane*16 + 8 + i]  = accn[i];
        part[lane*16 + 12 + i] = accgi[i];
      }
    }
    __syncthreads();
    if (wv == 0 && lane < 16) {           // D rows 0..3 = the 4 samples
      unsigned short* dst = h_buf + (size_t)(rb^1)*B_*HE_;
      #pragma unroll
      for (int i = 0; i < 4; ++i) {
        int s = i;
        float ar  = accr[i]  + part[lane*16 + i];
        float az  = accz[i]  + part[lane*16 + 4 + i];
        float an  = accn[i]  + part[lane*16 + 8 + i];
        float agi = accgi[i] + part[lane*16 + 12 + i];
        float r = sigm_(ar + br_b);
        float z = sigm_(az + bz_b);
        float n = tanh_(agi + bin_b + r*(an + bhn_b));
        float hn = (1.f - z)*n + z*hreg[i];
        hreg[i] = hn;
        dst[(size_t)(gs+s)*HE_ + cl] = f2b(hn);
        if (t == 127) h_enc[(size_t)(gs+s)*HE_ + cl] = hn;
      }
    }
    __syncthreads();
    if (tid == 0)
      __hip_atomic_fetch_add(&bar[(g<<7)+t], 1u, __ATOMIC_ACQ_REL, __HIP_MEMORY_SCOPE_AGENT);
  }
}

// ---------------- latent: mu / logstd / z ----------------
__global__ __launch_bounds__(64) void k_latent(
    const float* __restrict__ h_enc, const float* __restrict__ to_mu,
    const float* __restrict__ to_ls, const float* __restrict__ ls_bias,
    const float* __restrict__ eps, float* __restrict__ out_mu,
    float* __restrict__ out_ls, float* __restrict__ z_lat)
{
  __shared__ float hb[512];
  int b = blockIdx.x, tid = threadIdx.x;
  #pragma unroll
  for (int j = 0; j < 8; ++j) hb[j*64 + tid] = h_enc[(size_t)b*HE_ + j*64 + tid];
  __syncthreads();
  if (tid < 12) {
    float m = 0.f, s = 0.f;
    #pragma unroll 8
    for (int k = 0; k < 512; ++k) {
      float h = hb[k];
      m += h * to_mu[k*12 + tid];
      s += h * to_ls[k*12 + tid];
    }
    s += ls_bias[tid];
    out_mu[b*12 + tid] = m;
    out_ls[b*12 + tid] = s;
    z_lat[b*12 + tid] = m + eps[b*12 + tid] * __expf(s);
  }
}

// ---------------- hidden = tanh(z@W1+b1)@W2+b2, stored transposed [64k][64b] ----
__global__ __launch_bounds__(512) void k_hidden(
    const float* __restrict__ z_lat, const float* __restrict__ W1, const float* __restrict__ b1,
    const float* __restrict__ W2, const float* __restrict__ b2, float* __restrict__ hidden_T)
{
  __shared__ float zl[12];
  __shared__ float a[512];
  int b = blockIdx.x, tid = threadIdx.x;
  if (tid < 12) zl[tid] = z_lat[b*12 + tid];
  __syncthreads();
  float acc = b1[tid];
  #pragma unroll
  for (int k = 0; k < 12; ++k) acc += zl[k] * W1[k*512 + tid];
  a[tid] = tanh_(acc);
  __syncthreads();
  if (tid < 64) {
    float h = b2[tid];
    #pragma unroll 8
    for (int j = 0; j < 512; ++j) h += a[j] * W2[j*64 + tid];
    hidden_T[tid*64 + b] = h;
  }
}

// ---------------- psi expansion: whh -> int8 frags (32 samples/block) --------
// whh blocks: 2048 = (kt 32) x (cp 32) x (bhalf 2). amax via lane-butterfly +
// 1 atomic/wave; quantize to LDS; coalesced dwordx4 writeout.
__global__ __launch_bounds__(1024) void k_psi(
    const float* __restrict__ hidden_T, const float* __restrict__ W3, const float* __restrict__ b3,
    signed char* __restrict__ whh_q, float* __restrict__ scales, float* __restrict__ params)
{
  __shared__ float hid[64*64];
  __shared__ unsigned lmax[32];
  __shared__ __align__(16) signed char qtile[32*1024];
  int tid = threadIdx.x, blk = blockIdx.x;
  if (tid < 32) lmax[tid] = 0;
  #pragma unroll
  for (int j = 0; j < 4; ++j) hid[j*1024 + tid] = hidden_T[j*1024 + tid];
  __syncthreads();
  bool is_whh = blk < 2048;
  if (is_whh) {
    int kt = blk >> 6, cp = (blk >> 1) & 31, bh = blk & 1;
    int i_loc = tid >> 5, c_loc = tid & 31;
    size_t j = (size_t)(kt*32 + i_loc)*1024 + cp*32 + c_loc;
    float bv = b3[j];
    float acc[32];
    #pragma unroll
    for (int b = 0; b < 32; ++b) acc[b] = bv;
    for (int k = 0; k < 64; ++k) {
      float wv = W3[(size_t)k*NPSI_ + j];
      #pragma unroll
      for (int bq = 0; bq < 8; ++bq) {
        f32x4 h4 = *(const f32x4*)(&hid[k*64 + bh*32 + bq*4]);
        acc[bq*4+0] += wv * h4[0];
        acc[bq*4+1] += wv * h4[1];
        acc[bq*4+2] += wv * h4[2];
        acc[bq*4+3] += wv * h4[3];
      }
    }
    #pragma unroll
    for (int b = 0; b < 32; ++b) {
      float av = fabsf(acc[b]);
      #pragma unroll
      for (int d = 1; d < 64; d <<= 1) av = fmaxf(av, __shfl_xor(av, d));
      if ((tid & 63) == 0) atomicMax(&lmax[b], __float_as_uint(av));
    }
    __syncthreads();
    int l = (c_loc & 15) + (((i_loc>>3)&3)<<4);
    int jj = i_loc & 7;
    int base_lds = ((c_loc>>4)<<9) + l*8 + jj;
    #pragma unroll
    for (int b = 0; b < 32; ++b) {
      float m = __uint_as_float(lmax[b]);
      float inv = (m > 0.f) ? (127.f/m) : 0.f;
      qtile[b*1024 + base_lds] = (signed char)(int)rintf(acc[b]*inv);
    }
    __syncthreads();
    #pragma unroll
    for (int it = 0; it < 2; ++it) {
      int qid = it*1024 + tid;
      int b = qid >> 6, c64 = qid & 63;
      i32x4 v = *(const i32x4*)(&qtile[b*1024 + c64*16]);
      size_t goff = (size_t)(bh*32 + b)*1048576
                  + (size_t)((2*cp + (c64>>5))*32 + kt)*512 + (c64&31)*16;
      *(i32x4*)(whh_q + goff) = v;
    }
    if (tid < 32)
      scales[(size_t)(bh*32 + tid)*1024 + kt*32 + cp] = __uint_as_float(lmax[tid]);
  } else {
    size_t j = (size_t)1048576 + (size_t)(blk - 2048)*1024 + tid;
    float bv = b3[j];
    float acc[64];
    #pragma unroll
    for (int b = 0; b < 64; ++b) acc[b] = bv;
    for (int k = 0; k < 64; ++k) {
      float wv = W3[(size_t)k*NPSI_ + j];
      #pragma unroll
      for (int bq = 0; bq < 16; ++bq) {
        f32x4 h4 = *(const f32x4*)(&hid[k*64 + bq*4]);
        acc[bq*4+0] += wv * h4[0];
        acc[bq*4+1] += wv * h4[1];
        acc[bq*4+2] += wv * h4[2];
        acc[bq*4+3] += wv * h4[3];
      }
    }
    size_t off = j - 1048576;
    #pragma unroll
    for (int b = 0; b < 64; ++b)
      params[(size_t)b*PPS_ + off] = acc[b];
  }
}

// ---------------- decoder: 8 groups x 32 blocks x 8 waves; all-int8 streams
// XCD-remapped blocks (same-bg co-located -> gru L2-resident). Chunks of 4 kt
// (5 glds, 5 KB), static ping-pong, counted vmcnt(5), post-store prefetch.
__global__ __launch_bounds__(512, 2) void k_decoder(
    const float* __restrict__ inputs, const float* __restrict__ gru_Wih,
    const float* __restrict__ gru_bias,
    const signed char* __restrict__ whh_q, const float* __restrict__ scales,
    const signed char* __restrict__ gru_q, const float* __restrict__ scales_g,
    const float* __restrict__ params,
    unsigned short* __restrict__ h_buf, float* __restrict__ dec,
    float* __restrict__ out_states, unsigned int* __restrict__ bar)
{
  __shared__ __align__(16) unsigned short h_bf[8*1048];   // stride 2096 B
  __shared__ __align__(16) signed char h_q8[8*1040];      // stride 1040 B
  __shared__ __align__(16) char stg[8][2][5120];          // 80 KB
  __shared__ unsigned short wih_lds[8192];  // [s][i][c32] bf16
  __shared__ unsigned short gwih_lds[2048]; // [i][gate*32+c] bf16
  __shared__ float x_lds[256];
  __shared__ float gh_lds[1024];            // [w][sample][col16]
  __shared__ float mv_lds[256];             // [sample][col32]
  __shared__ float sc_lds[256];             // [w][kt] whh premult scale
  __shared__ float sgr_lds[128];            // [w][16kt] gru premult scale
  int tid = threadIdx.x;
  // XCD remap: same-bg blocks land on same XCD (round-robin i%8 assumption)
  int i_b = blockIdx.x;
  int g = (i_b >> 3) & 7, bg = (i_b & 7) + ((i_b >> 6) << 3);
  int c0 = bg*32, gs = g*8;
  int w = tid >> 6, lane = tid & 63;
  int s_t = (tid >> 5) & 7, c_t = tid & 31;     // epilogue mapping (tid<256)
  int sg_t = gs + s_t, cg_t = c0 + c_t;
  float bh_r = 0.f, br_b = 0.f, bz_b = 0.f;
  if (tid < 256) {
    bh_r = params[(size_t)sg_t*PPS_ + cg_t];
    br_b = gru_bias[cg_t];
    bz_b = gru_bias[1024 + cg_t];
  }
  for (int idx = tid; idx < 2048; idx += 512) {
    int i = idx >> 6, gc = idx & 63;
    gwih_lds[idx] = f2b(gru_Wih[i*2048 + (gc>>5)*1024 + c0 + (gc&31)]);
  }
  for (int idx = tid; idx < 8192; idx += 512) {
    int s = idx >> 10, r = idx & 1023;
    wih_lds[idx] = f2b(params[(size_t)(gs+s)*PPS_ + 1024 + (r>>5)*1024 + c0 + (r&31)]);
  }
  if (lane < 32)
    sc_lds[w*32 + lane] = scales[(size_t)(gs+w)*1024 + lane*32 + bg] * (1.f/16129.f);
  int j_t = w >> 1;                              // gh tile 0..3
  int nt_j = (j_t < 2) ? (2*bg + j_t) : (64 + 2*bg + (j_t - 2));
  if (lane < 16)
    sgr_lds[w*16 + lane] = scales_g[nt_j*32 + (w&1)*16 + lane] * (1.f/16129.f);
  // wave-private stream bases (+ lane*16 for glds)
  const char* af0c = (const char*)whh_q + (size_t)((gs+w)*64 + 2*bg)*16384 + lane*16;
  const char* af1c = af0c + 16384;
  const char* gfc = (const char*)gru_q + ((size_t)nt_j*32 + (w&1)*16)*512 + lane*16;
  int ho_l = (lane>>4)<<3;
  int ghk0 = (w&1)*16;
  char* bufA = &stg[w][0][0];
  char* bufB = &stg[w][1][0];

  auto ISSUE = [&](char* bufp, int cc) {   // one 4-kt chunk: 5 x 1KB glds
    const char* a0 = af0c + (size_t)cc*2048;
    const char* a1 = af1c + (size_t)cc*2048;
    glds16(a0,        bufp);        glds16(a0 + 1024, bufp + 1024);
    glds16(a1,        bufp + 2048); glds16(a1 + 1024, bufp + 3072);
    glds16(gfc + (size_t)cc*1024, bufp + 4096);
  };
  f32x4 aghf, facc0, facc1;
  auto HALF = [&](char* bufp, int c, int doIssue) {
    asm volatile("s_waitcnt vmcnt(5)" ::: "memory");   // chunk c landed
    long a00 = *(const long*)(bufp + 0*512 + lane*8);
    long a01 = *(const long*)(bufp + 1*512 + lane*8);
    long a02 = *(const long*)(bufp + 2*512 + lane*8);
    long a03 = *(const long*)(bufp + 3*512 + lane*8);
    long a10 = *(const long*)(bufp + 2048 + 0*512 + lane*8);
    long a11 = *(const long*)(bufp + 2048 + 1*512 + lane*8);
    long a12 = *(const long*)(bufp + 2048 + 2*512 + lane*8);
    long a13 = *(const long*)(bufp + 2048 + 3*512 + lane*8);
    long qg0 = *(const long*)(bufp + 4096 + lane*8);
    long qg1 = *(const long*)(bufp + 4608 + lane*8);
    long hq0 = *(const long*)(h_q8 + w*1040 + (4*c+0)*32 + ho_l);
    long hq1 = *(const long*)(h_q8 + w*1040 + (4*c+1)*32 + ho_l);
    long hq2 = *(const long*)(h_q8 + w*1040 + (4*c+2)*32 + ho_l);
    long hq3 = *(const long*)(h_q8 + w*1040 + (4*c+3)*32 + ho_l);
    long haq0 = *(const long*)(h_q8 + (lane&15)*1040 + (ghk0 + 2*c)*32 + ho_l);
    long haq1 = *(const long*)(h_q8 + (lane&15)*1040 + (ghk0 + 2*c+1)*32 + ho_l);
    float s0 = sc_lds[w*32 + 4*c + 0];
    float s1 = sc_lds[w*32 + 4*c + 1];
    float s2 = sc_lds[w*32 + 4*c + 2];
    float s3 = sc_lds[w*32 + 4*c + 3];
    float g0 = sgr_lds[w*16 + 2*c], g1 = sgr_lds[w*16 + 2*c + 1];
    asm volatile("s_waitcnt lgkmcnt(0)" ::: "memory"); // all reads done
    __builtin_amdgcn_sched_barrier(0);
    if (doIssue) ISSUE(bufp, c + 2);
    i32x4 z4 = {0,0,0,0};
    i32x4 q;
    q = __builtin_amdgcn_mfma_i32_16x16x32_i8(a00, hq0, z4, 0,0,0);
    #pragma unroll
    for (int e = 0; e < 4; ++e) facc0[e] += (float)q[e]*s0;
    q = __builtin_amdgcn_mfma_i32_16x16x32_i8(a01, hq1, z4, 0,0,0);
    #pragma unroll
    for (int e = 0; e < 4; ++e) facc0[e] += (float)q[e]*s1;
    q = __builtin_amdgcn_mfma_i32_16x16x32_i8(a02, hq2, z4, 0,0,0);
    #pragma unroll
    for (int e = 0; e < 4; ++e) facc0[e] += (float)q[e]*s2;
    q = __builtin_amdgcn_mfma_i32_16x16x32_i8(a03, hq3, z4, 0,0,0);
    #pragma unroll
    for (int e = 0; e < 4; ++e) facc0[e] += (float)q[e]*s3;
    q = __builtin_amdgcn_mfma_i32_16x16x32_i8(a10, hq0, z4, 0,0,0);
    #pragma unroll
    for (int e = 0; e < 4; ++e) facc1[e] += (float)q[e]*s0;
    q = __builtin_amdgcn_mfma_i32_16x16x32_i8(a11, hq1, z4, 0,0,0);
    #pragma unroll
    for (int e = 0; e < 4; ++e) facc1[e] += (float)q[e]*s1;
    q = __builtin_amdgcn_mfma_i32_16x16x32_i8(a12, hq2, z4, 0,0,0);
    #pragma unroll
    for (int e = 0; e < 4; ++e) facc1[e] += (float)q[e]*s2;
    q = __builtin_amdgcn_mfma_i32_16x16x32_i8(a13, hq3, z4, 0,0,0);
    #pragma unroll
    for (int e = 0; e < 4; ++e) facc1[e] += (float)q[e]*s3;
    q = __builtin_amdgcn_mfma_i32_16x16x32_i8(haq0, qg0, z4, 0,0,0);
    #pragma unroll
    for (int e = 0; e < 4; ++e) aghf[e] += (float)q[e]*g0;
    q = __builtin_amdgcn_mfma_i32_16x16x32_i8(haq1, qg1, z4, 0,0,0);
    #pragma unroll
    for (int e = 0; e < 4; ++e) aghf[e] += (float)q[e]*g1;
  };

  __syncthreads();
  ISSUE(bufA, 0); ISSUE(bufB, 1);   // prologue: 2 chunks in flight
  for (int t = 0; t < 128; ++t) {
    int rb = t & 1;
    if (t > 0 && tid == 0) {
      while (__hip_atomic_load(&bar[(g<<7)+(t-1)], __ATOMIC_ACQUIRE, __HIP_MEMORY_SCOPE_AGENT) < 32u)
        __builtin_amdgcn_s_sleep(1);
    }
    __builtin_amdgcn_s_barrier();
    { // stage h: wave w stages its sample (2 KB)
      const char* hs = (const char*)(h_buf + (size_t)rb*B_*HD_ + (size_t)(gs + w)*HD_) + lane*16;
      glds16(hs,        &h_bf[w*1048]);
      glds16(hs + 1024, &h_bf[w*1048 + 512]);
    }
    if (tid < 256) x_lds[tid] = inputs[((size_t)sg_t*T_ + t)*DIN_ + c_t];
    asm volatile("s_waitcnt vmcnt(0)" ::: "memory");   // h + x + prefetch landed
    __builtin_amdgcn_s_barrier();
    { // wave-local: quantize own sample's h to int8 (scale 127, |h|<=1)
      i32x4 pk;
      #pragma unroll
      for (int hh = 0; hh < 2; ++hh) {
        bf16x8 hv = *(const bf16x8*)(&h_bf[w*1048 + lane*16 + hh*8]);
        int lo = 0, hi2 = 0;
        #pragma unroll
        for (int e = 0; e < 4; ++e) {
          int q = (int)rintf(b2f((unsigned short)hv[e]) * 127.f);
          lo |= (q & 255) << (8*e);
        }
        #pragma unroll
        for (int e = 0; e < 4; ++e) {
          int q = (int)rintf(b2f((unsigned short)hv[4+e]) * 127.f);
          hi2 |= (q & 255) << (8*e);
        }
        pk[2*hh] = lo; pk[2*hh+1] = hi2;
      }
      *(i32x4*)(h_q8 + w*1040 + lane*16) = pk;
    }
    asm volatile("s_waitcnt lgkmcnt(0)" ::: "memory");
    __builtin_amdgcn_s_barrier();   // h_q8 all rows visible (gh reads cross-wave)
    aghf = (f32x4){0,0,0,0}; facc0 = (f32x4){0,0,0,0}; facc1 = (f32x4){0,0,0,0};
    #pragma unroll 1
    for (int i2 = 0; i2 < 3; ++i2) {   // chunks 0..5 (with refill)
      HALF(bufA, 2*i2, 1);
      HALF(bufB, 2*i2 + 1, 1);
    }
    HALF(bufA, 6, 0);
    asm volatile("s_waitcnt vmcnt(0)" ::: "memory");
    HALF(bufB, 7, 0);
    // exchange partials
    if (lane < 32) {          // gh D rows 0..7 = samples, cols = lane&15
      #pragma unroll
      for (int i = 0; i < 4; ++i)
        gh_lds[w*128 + ((lane>>4)*4 + i)*16 + (lane&15)] = aghf[i];
    }
    if ((lane & 15) == 0) {   // mv valid at n=0; rows = col-in-tile
      int cb = (lane>>4)*4;
      #pragma unroll
      for (int i = 0; i < 4; ++i) {
        mv_lds[w*32 + cb + i]      = facc0[i];
        mv_lds[w*32 + 16 + cb + i] = facc1[i];
      }
    }
    asm volatile("s_waitcnt lgkmcnt(0)" ::: "memory");
    __builtin_amdgcn_s_barrier();
    if (tid < 256) {
      int jr = c_t >> 4, cl16 = c_t & 15;
      float ghr = gh_lds[(2*jr)*128   + s_t*16 + cl16] + gh_lds[(2*jr+1)*128 + s_t*16 + cl16];
      float ghz = gh_lds[(4+2*jr)*128 + s_t*16 + cl16] + gh_lds[(5+2*jr)*128 + s_t*16 + cl16];
      float gxr = 0.f, gxz = 0.f, ex = 0.f;
      #pragma unroll 8
      for (int i = 0; i < 32; ++i) {
        float xv = x_lds[s_t*32 + i];
        gxr += xv * b2f(gwih_lds[i*64 + c_t]);
        gxz += xv * b2f(gwih_lds[i*64 + 32 + c_t]);
        ex  += xv * b2f(wih_lds[s_t*1024 + i*32 + c_t]);
      }
      float r = sigm_(gxr + ghr + br_b);
      float z = sigm_(gxz + ghz + bz_b);
      float eta = tanh_(ex + bh_r + r * mv_lds[s_t*32 + c_t]);
      float ho_ = b2f(h_bf[s_t*1048 + c0 + c_t]);
      float hn = z*ho_ + (1.f - z)*eta;
      dec[((size_t)sg_t*T_ + t)*HD_ + cg_t] = hn;
      h_buf[(size_t)(rb^1)*B_*HD_ + (size_t)sg_t*HD_ + cg_t] = f2b(hn);
      if (t == 127) out_states[(size_t)sg_t*HD_ + cg_t] = hn;
    }
    if (t < 127) {
      ISSUE(bufA, 0); ISSUE(bufB, 1);    // next step's chunks overlap spin
      asm volatile("s_waitcnt vmcnt(10)" ::: "memory");  // stores drained (oldest)
    } else {
      asm volatile("s_waitcnt vmcnt(0)" ::: "memory");
    }
    __builtin_amdgcn_s_barrier();
    if (t < 127 && tid == 0)
      __hip_atomic_fetch_add(&bar[(g<<7)+t], 1u, __ATOMIC_ACQ_REL, __HIP_MEMORY_SCOPE_AGENT);
  }
}

// ---------------- yhats = dec @ C_b + concat(x, x @ D_b) ----------------
__global__ __launch_bounds__(256) void k_yhats(
    const float* __restrict__ dec, const float* __restrict__ inputs,
    const float* __restrict__ params, float* __restrict__ out_y)
{
  __shared__ __align__(16) float dsm[8*1024];
  __shared__ float xr[8*32];
  int blk = blockIdx.x, tid = threadIdx.x;
  int b = blk >> 4, t8 = (blk & 15) * 8;
  const float* prm = params + (size_t)b*PPS_;
  const float* C = prm + 33792;
  const float* D = prm + 99328;
  #pragma unroll
  for (int j = 0; j < 8; ++j) {
    int ch = j*256 + tid;
    *(f32x4*)(&dsm[ch*4]) = *(const f32x4*)(dec + ((size_t)b*T_ + t8)*HD_ + ch*4);
  }
  {
    int tl = tid >> 5, i = tid & 31;
    xr[tl*32 + i] = inputs[((size_t)b*T_ + t8 + tl)*DIN_ + i];
    xr[(tl+4)*32 + i] = inputs[((size_t)b*T_ + t8 + tl + 4)*DIN_ + i];
  }
  __syncthreads();
  int o = tid & 63;
  int tl0 = (tid >> 6) * 2;
  float a0 = 0.f, a1 = 0.f;
  #pragma unroll 4
  for (int h = 0; h < 1024; ++h) {
    float cv = C[h*64 + o];
    a0 += dsm[tl0*1024 + h] * cv;
    a1 += dsm[(tl0+1)*1024 + h] * cv;
  }
  float r0, r1;
  if (o < 32) {
    r0 = xr[tl0*32 + o];
    r1 = xr[(tl0+1)*32 + o];
  } else {
    r0 = 0.f; r1 = 0.f;
    #pragma unroll 8
    for (int i = 0; i < 32; ++i) {
      float dv = D[i*32 + (o-32)];
      r0 += xr[tl0*32 + i] * dv;
      r1 += xr[(tl0+1)*32 + i] * dv;
    }
  }
  out_y[((size_t)b*T_ + t8 + tl0)*DOUT_ + o]     = a0 + r0;
  out_y[((size_t)b*T_ + t8 + tl0 + 1)*DOUT_ + o] = a1 + r1;
}

extern "C" void kernel_launch(void* const* d_in, const int* in_sizes, int n_in,
                              void* d_out, int out_size, void* d_ws, size_t ws_size,
                              hipStream_t stream)
{
  const float* inputs  = (const float*)d_in[0];
  const float* outputs = (const float*)d_in[1];
  const float* eps     = (const float*)d_in[2];
  const float* state   = (const float*)d_in[3];
  const float* enc_Wih = (const float*)d_in[4];
  const float* enc_Whh = (const float*)d_in[5];
  const float* enc_bih = (const float*)d_in[6];
  const float* enc_bhh = (const float*)d_in[7];
  const float* to_mu   = (const float*)d_in[8];
  const float* to_ls   = (const float*)d_in[9];
  const float* to_lsb  = (const float*)d_in[10];
  const float* psi_W1  = (const float*)d_in[11];
  const float* psi_b1  = (const float*)d_in[12];
  const float* psi_W2  = (const float*)d_in[13];
  const float* psi_b2  = (const float*)d_in[14];
  const float* psi_W3  = (const float*)d_in[15];
  const float* psi_b3  = (const float*)d_in[16];
  const float* gru_Wih = (const float*)d_in[17];
  const float* gru_Whh = (const float*)d_in[18];
  const float* gru_bias= (const float*)d_in[19];
  float* out    = (float*)d_out;
  float* out_y  = out;
  float* out_mu = out + 524288;
  float* out_ls = out + 525056;
  float* out_st = out + 525824;

  if (ws_size < 130000000) return;  // fail loudly rather than corrupt
  char* ws = (char*)d_ws;
  size_t off = 0;
  auto alloc = [&](size_t bytes)->char*{ char* p = ws + off; off += (bytes + 255) & ~(size_t)255; return p; };
  signed char* whh_q      = (signed char*)alloc(67108864);
  float* scales           = (float*)alloc(262144);
  unsigned short* encW_f  = (unsigned short*)alloc(1572864);
  unsigned short* encI_f  = (unsigned short*)alloc(196608);
  signed char* gru_q      = (signed char*)alloc(2097152);
  float* scales_g         = (float*)alloc(16384);
  float* params           = (float*)alloc(25690112);
  float* h_enc            = (float*)alloc(131072);
  float* z_lat            = (float*)alloc(3072);
  float* hidden_T         = (float*)alloc(16384);
  unsigned short* h_buf_e = (unsigned short*)alloc(131072);
  unsigned short* h_buf_d = (unsigned short*)alloc(262144);
  float* dec              = (float*)alloc(33554432);
  unsigned int* bar_e     = (unsigned int*)alloc(8192);
  unsigned int* bar_d     = (unsigned int*)alloc(8192);

  hipMemsetAsync(bar_e, 0, 8192, stream);
  hipMemsetAsync(bar_d, 0, 8192, stream);
  hipMemsetAsync(h_buf_e, 0, 131072, stream);

  k_prep<<<5888, 512, 0, stream>>>(enc_Whh, enc_Wih, gru_Whh, state, encW_f, encI_f, gru_q, scales_g, h_buf_d);
  k_encoder<<<512, 128, 0, stream>>>(outputs, enc_bih, enc_bhh, encW_f, encI_f, h_buf_e, h_enc, bar_e);
  k_latent<<<64, 64, 0, stream>>>(h_enc, to_mu, to_ls, to_lsb, eps, out_mu, out_ls, z_lat);
  k_hidden<<<64, 512, 0, stream>>>(z_lat, psi_W1, psi_b1, psi_W2, psi_b2, hidden_T);
  k_psi<<<2146, 1024, 0, stream>>>(hidden_T, psi_W3, psi_b3, whh_q, scales, params);
  k_decoder<<<256, 512, 0, stream>>>(inputs, gru_Wih, gru_bias, whh_q, scales, gru_q, scales_g, params, h_buf_d, dec, out_st, bar_d);
  k_yhats<<<1024, 256, 0, stream>>>(dec, inputs, params, out_y);
}

// Round 10
// 5304.480 us; speedup vs baseline: 1.0516x; 1.0516x over previous
//
#include <hip/hip_runtime.h>
#include <stdint.h>

#define B_ 64
#define T_ 128
#define DIN_ 32
#define DOUT_ 64
#define HE_ 512
#define HD_ 1024
#define NPSI_ 1148928
#define PPS_ 100352   // per-sample non-Whh params (floats): bh[1024] Wih[32*1024] C[1024*64] D[32*32]

typedef short bf16x8 __attribute__((ext_vector_type(8)));
typedef float f32x4 __attribute__((ext_vector_type(4)));
typedef int   i32x4 __attribute__((ext_vector_type(4)));

__device__ __forceinline__ unsigned short f2b(float f){
  unsigned u = __float_as_uint(f);
  u += 0x7fffu + ((u>>16)&1u);      // round-to-nearest-even bf16
  return (unsigned short)(u>>16);
}
__device__ __forceinline__ float b2f(unsigned short s){
  return __uint_as_float(((unsigned)s)<<16);
}
__device__ __forceinline__ float sigm_(float x){
  float e = __expf(-x);
  return 1.f/(1.f+e);
}
__device__ __forceinline__ float tanh_(float x){
  float e = __expf(2.f*x);
  return 1.f - 2.f/(e+1.f);         // safe at +-inf
}
// async global->LDS: 64 lanes x 16 B = 1 KB; LDS dest wave-uniform, global
// src per-lane. Counts in vmcnt.
__device__ __forceinline__ void glds16(const void* g, void* l) {
  __builtin_amdgcn_global_load_lds(
      (const __attribute__((address_space(1))) unsigned int*)g,
      (__attribute__((address_space(3))) unsigned int*)l, 16, 0, 0);
}

// ---------------- prep: bf16 frag swizzles, gru int8 quant, h_dec init ------
__global__ __launch_bounds__(512) void k_prep(
    const float* __restrict__ enc_Whh, const float* __restrict__ enc_Wih,
    const float* __restrict__ gru_Whh, const float* __restrict__ state,
    unsigned short* __restrict__ encW_f, unsigned short* __restrict__ encI_f,
    signed char* __restrict__ gru_q, float* __restrict__ scales_g,
    unsigned short* __restrict__ h_dec)
{
  __shared__ unsigned gmax_s;
  __shared__ __align__(16) signed char gq[512];
  int blk = blockIdx.x, tid = threadIdx.x;
  if (blk < 1536) {                       // enc_Whh: gh = h @ Whh^T -> B[k][n]=Whh[n][k]
    int nt = blk >> 4, kt = blk & 15;
    int c = tid >> 5, k = tid & 31;
    float v = enc_Whh[(size_t)(nt*16 + c)*HE_ + kt*32 + k];
    int l = c + ((k>>3)<<4), jj = k & 7;
    encW_f[(size_t)(nt*16 + kt)*512 + l*8 + jj] = f2b(v);
  } else if (blk < 1728) {                // enc_Wih: B[k][n]=Wih[n][k]
    int f = blk - 1536; int nt = f >> 1, kt = f & 1;
    int c = tid >> 5, k = tid & 31;
    float v = enc_Wih[(size_t)(nt*16 + c)*DOUT_ + kt*32 + k];
    int l = c + ((k>>3)<<4), jj = k & 7;
    encI_f[(size_t)(nt*2 + kt)*512 + l*8 + jj] = f2b(v);
  } else if (blk < 5824) {                // gru_Whh -> int8 frags + per-tile scale
    int f = blk - 1728; int nt = f >> 5, kt = f & 31;
    int k = tid >> 4, c = tid & 15;
    float v = gru_Whh[(size_t)(kt*32 + k)*2048 + nt*16 + c];
    int l = c + ((k>>3)<<4), jj = k & 7;
    if (tid == 0) gmax_s = 0;
    __syncthreads();
    float av = fabsf(v);
    #pragma unroll
    for (int d = 1; d < 64; d <<= 1) av = fmaxf(av, __shfl_xor(av, d));
    if ((tid & 63) == 0) atomicMax(&gmax_s, __float_as_uint(av));
    __syncthreads();
    float m = __uint_as_float(gmax_s);
    float inv = (m > 0.f) ? (127.f/m) : 0.f;
    gq[l*8 + jj] = (signed char)(int)rintf(v*inv);
    __syncthreads();
    if (tid < 32)
      *(i32x4*)(gru_q + (size_t)(nt*32 + kt)*512 + tid*16) = *(const i32x4*)(&gq[tid*16]);
    if (tid == 0) scales_g[nt*32 + kt] = m;
  } else {                                // h_dec buf0 init from `state`
    int b = blk - 5824;
    h_dec[(size_t)b*HD_ + tid]       = f2b(state[(size_t)b*HD_ + tid]);
    h_dec[(size_t)b*HD_ + 512 + tid] = f2b(state[(size_t)b*HD_ + 512 + tid]);
  }
}

// ---------------- encoder: 16 groups x 32 blocks x 2 waves (K-split), 4 samples
__global__ __launch_bounds__(128) void k_encoder(
    const float* __restrict__ outputs, const float* __restrict__ bih, const float* __restrict__ bhh,
    const unsigned short* __restrict__ encW_f, const unsigned short* __restrict__ encI_f,
    unsigned short* __restrict__ h_buf, float* __restrict__ h_enc, unsigned int* __restrict__ bar)
{
  __shared__ __align__(16) unsigned short h_bf[16*520];   // rows 4-15 stay zero
  __shared__ __align__(16) unsigned short xa[16*72];
  __shared__ float part[64*16];                           // wave1 partial accs
  int tid = threadIdx.x, wv = tid >> 6, lane = tid & 63;
  int g = blockIdx.x >> 5, bg = blockIdx.x & 31;
  int c0 = bg*16, gs = g*4;
  for (int i = tid; i < 16*520; i += 128) h_bf[i] = 0;
  for (int i = tid; i < 16*72; i += 128) xa[i] = 0;
  int cl = c0 + (lane & 15);
  float br_b = bih[cl] + bhh[cl];
  float bz_b = bih[512+cl] + bhh[512+cl];
  float bin_b = bih[1024+cl];
  float bhn_b = bhh[1024+cl];
  float hreg[4] = {0.f,0.f,0.f,0.f};
  int nt_r = bg, nt_z = 32+bg, nt_n = 64+bg;
  __syncthreads();
  for (int t = 0; t < 128; ++t) {
    int rb = t & 1;
    if (t > 0) {
      if (tid == 0) {
        while (__hip_atomic_load(&bar[(g<<7)+(t-1)], __ATOMIC_ACQUIRE, __HIP_MEMORY_SCOPE_AGENT) < 32u)
          __builtin_amdgcn_s_sleep(2);
      }
      __syncthreads();
    }
    { // reload h (4 samples x 512 bf16) + x_t
      const unsigned short* src = h_buf + (size_t)rb*B_*HE_ + (size_t)gs*HE_;
      #pragma unroll
      for (int j = 0; j < 2; ++j) {
        int chunk = j*128 + tid;
        bf16x8 v = *(const bf16x8*)(src + chunk*8);
        int s = chunk >> 6, col = (chunk & 63) * 8;
        *(bf16x8*)(&h_bf[s*520 + col]) = v;
      }
      #pragma unroll
      for (int j = 0; j < 2; ++j) {
        int e = j*128 + tid;
        int s = e >> 6, d = e & 63;
        xa[s*72 + d] = f2b(outputs[((size_t)(gs+s)*T_ + t)*DOUT_ + d]);
      }
    }
    __syncthreads();
    f32x4 accr = {0,0,0,0}, accz = {0,0,0,0}, accn = {0,0,0,0}, accgi = {0,0,0,0};
    { // gi = x @ Wih^T, kt = wv
      bf16x8 a = *(const bf16x8*)(&xa[(lane&15)*72 + wv*32 + ((lane>>4)<<3)]);
      bf16x8 b0 = *(const bf16x8*)(encI_f + (size_t)(nt_r*2+wv)*512 + lane*8);
      bf16x8 b1 = *(const bf16x8*)(encI_f + (size_t)(nt_z*2+wv)*512 + lane*8);
      bf16x8 b2 = *(const bf16x8*)(encI_f + (size_t)(nt_n*2+wv)*512 + lane*8);
      accr  = __builtin_amdgcn_mfma_f32_16x16x32_bf16(a, b0, accr, 0,0,0);
      accz  = __builtin_amdgcn_mfma_f32_16x16x32_bf16(a, b1, accz, 0,0,0);
      accgi = __builtin_amdgcn_mfma_f32_16x16x32_bf16(a, b2, accgi, 0,0,0);
    }
    #pragma unroll
    for (int kk = 0; kk < 8; ++kk) {      // gh = h @ Whh^T, K-half per wave
      int kt = wv*8 + kk;
      bf16x8 a = *(const bf16x8*)(&h_bf[(lane&15)*520 + kt*32 + ((lane>>4)<<3)]);
      bf16x8 b0 = *(const bf16x8*)(encW_f + (size_t)(nt_r*16+kt)*512 + lane*8);
      bf16x8 b1 = *(const bf16x8*)(encW_f + (size_t)(nt_z*16+kt)*512 + lane*8);
      bf16x8 b2 = *(const bf16x8*)(encW_f + (size_t)(nt_n*16+kt)*512 + lane*8);
      accr = __builtin_amdgcn_mfma_f32_16x16x32_bf16(a, b0, accr, 0,0,0);
      accz = __builtin_amdgcn_mfma_f32_16x16x32_bf16(a, b1, accz, 0,0,0);
      accn = __builtin_amdgcn_mfma_f32_16x16x32_bf16(a, b2, accn, 0,0,0);
    }
    if (wv == 1) {
      #pragma unroll
      for (int i = 0; i < 4; ++i) {
        part[lane*16 + i]      = accr[i];
        part[lane*16 + 4 + i]  = accz[i];
        part[lane*16 + 8 + i]  = accn[i];
        part[lane*16 + 12 + i] = accgi[i];
      }
    }
    __syncthreads();
    if (wv == 0 && lane < 16) {           // D rows 0..3 = the 4 samples
      unsigned short* dst = h_buf + (size_t)(rb^1)*B_*HE_;
      #pragma unroll
      for (int i = 0; i < 4; ++i) {
        int s = i;
        float ar  = accr[i]  + part[lane*16 + i];
        float az  = accz[i]  + part[lane*16 + 4 + i];
        float an  = accn[i]  + part[lane*16 + 8 + i];
        float agi = accgi[i] + part[lane*16 + 12 + i];
        float r = sigm_(ar + br_b);
        float z = sigm_(az + bz_b);
        float n = tanh_(agi + bin_b + r*(an + bhn_b));
        float hn = (1.f - z)*n + z*hreg[i];
        hreg[i] = hn;
        dst[(size_t)(gs+s)*HE_ + cl] = f2b(hn);
        if (t == 127) h_enc[(size_t)(gs+s)*HE_ + cl] = hn;
      }
    }
    __syncthreads();
    if (tid == 0)
      __hip_atomic_fetch_add(&bar[(g<<7)+t], 1u, __ATOMIC_ACQ_REL, __HIP_MEMORY_SCOPE_AGENT);
  }
}

// ---------------- latent: mu / logstd / z ----------------
__global__ __launch_bounds__(64) void k_latent(
    const float* __restrict__ h_enc, const float* __restrict__ to_mu,
    const float* __restrict__ to_ls, const float* __restrict__ ls_bias,
    const float* __restrict__ eps, float* __restrict__ out_mu,
    float* __restrict__ out_ls, float* __restrict__ z_lat)
{
  __shared__ float hb[512];
  int b = blockIdx.x, tid = threadIdx.x;
  #pragma unroll
  for (int j = 0; j < 8; ++j) hb[j*64 + tid] = h_enc[(size_t)b*HE_ + j*64 + tid];
  __syncthreads();
  if (tid < 12) {
    float m = 0.f, s = 0.f;
    #pragma unroll 8
    for (int k = 0; k < 512; ++k) {
      float h = hb[k];
      m += h * to_mu[k*12 + tid];
      s += h * to_ls[k*12 + tid];
    }
    s += ls_bias[tid];
    out_mu[b*12 + tid] = m;
    out_ls[b*12 + tid] = s;
    z_lat[b*12 + tid] = m + eps[b*12 + tid] * __expf(s);
  }
}

// ---------------- hidden = tanh(z@W1+b1)@W2+b2, stored transposed [64k][64b] ----
__global__ __launch_bounds__(512) void k_hidden(
    const float* __restrict__ z_lat, const float* __restrict__ W1, const float* __restrict__ b1,
    const float* __restrict__ W2, const float* __restrict__ b2, float* __restrict__ hidden_T)
{
  __shared__ float zl[12];
  __shared__ float a[512];
  int b = blockIdx.x, tid = threadIdx.x;
  if (tid < 12) zl[tid] = z_lat[b*12 + tid];
  __syncthreads();
  float acc = b1[tid];
  #pragma unroll
  for (int k = 0; k < 12; ++k) acc += zl[k] * W1[k*512 + tid];
  a[tid] = tanh_(acc);
  __syncthreads();
  if (tid < 64) {
    float h = b2[tid];
    #pragma unroll 8
    for (int j = 0; j < 512; ++j) h += a[j] * W2[j*64 + tid];
    hidden_T[tid*64 + b] = h;
  }
}

// ---------------- psi expansion: whh -> int8 frags (32 samples/block) --------
__global__ __launch_bounds__(1024) void k_psi(
    const float* __restrict__ hidden_T, const float* __restrict__ W3, const float* __restrict__ b3,
    signed char* __restrict__ whh_q, float* __restrict__ scales, float* __restrict__ params)
{
  __shared__ float hid[64*64];
  __shared__ unsigned lmax[32];
  __shared__ __align__(16) signed char qtile[32*1024];
  int tid = threadIdx.x, blk = blockIdx.x;
  if (tid < 32) lmax[tid] = 0;
  #pragma unroll
  for (int j = 0; j < 4; ++j) hid[j*1024 + tid] = hidden_T[j*1024 + tid];
  __syncthreads();
  bool is_whh = blk < 2048;
  if (is_whh) {
    int kt = blk >> 6, cp = (blk >> 1) & 31, bh = blk & 1;
    int i_loc = tid >> 5, c_loc = tid & 31;
    size_t j = (size_t)(kt*32 + i_loc)*1024 + cp*32 + c_loc;
    float bv = b3[j];
    float acc[32];
    #pragma unroll
    for (int b = 0; b < 32; ++b) acc[b] = bv;
    for (int k = 0; k < 64; ++k) {
      float wv = W3[(size_t)k*NPSI_ + j];
      #pragma unroll
      for (int bq = 0; bq < 8; ++bq) {
        f32x4 h4 = *(const f32x4*)(&hid[k*64 + bh*32 + bq*4]);
        acc[bq*4+0] += wv * h4[0];
        acc[bq*4+1] += wv * h4[1];
        acc[bq*4+2] += wv * h4[2];
        acc[bq*4+3] += wv * h4[3];
      }
    }
    #pragma unroll
    for (int b = 0; b < 32; ++b) {
      float av = fabsf(acc[b]);
      #pragma unroll
      for (int d = 1; d < 64; d <<= 1) av = fmaxf(av, __shfl_xor(av, d));
      if ((tid & 63) == 0) atomicMax(&lmax[b], __float_as_uint(av));
    }
    __syncthreads();
    int l = (c_loc & 15) + (((i_loc>>3)&3)<<4);
    int jj = i_loc & 7;
    int base_lds = ((c_loc>>4)<<9) + l*8 + jj;
    #pragma unroll
    for (int b = 0; b < 32; ++b) {
      float m = __uint_as_float(lmax[b]);
      float inv = (m > 0.f) ? (127.f/m) : 0.f;
      qtile[b*1024 + base_lds] = (signed char)(int)rintf(acc[b]*inv);
    }
    __syncthreads();
    #pragma unroll
    for (int it = 0; it < 2; ++it) {
      int qid = it*1024 + tid;
      int b = qid >> 6, c64 = qid & 63;
      i32x4 v = *(const i32x4*)(&qtile[b*1024 + c64*16]);
      size_t goff = (size_t)(bh*32 + b)*1048576
                  + (size_t)((2*cp + (c64>>5))*32 + kt)*512 + (c64&31)*16;
      *(i32x4*)(whh_q + goff) = v;
    }
    if (tid < 32)
      scales[(size_t)(bh*32 + tid)*1024 + kt*32 + cp] = __uint_as_float(lmax[tid]);
  } else {
    size_t j = (size_t)1048576 + (size_t)(blk - 2048)*1024 + tid;
    float bv = b3[j];
    float acc[64];
    #pragma unroll
    for (int b = 0; b < 64; ++b) acc[b] = bv;
    for (int k = 0; k < 64; ++k) {
      float wv = W3[(size_t)k*NPSI_ + j];
      #pragma unroll
      for (int bq = 0; bq < 16; ++bq) {
        f32x4 h4 = *(const f32x4*)(&hid[k*64 + bq*4]);
        acc[bq*4+0] += wv * h4[0];
        acc[bq*4+1] += wv * h4[1];
        acc[bq*4+2] += wv * h4[2];
        acc[bq*4+3] += wv * h4[3];
      }
    }
    size_t off = j - 1048576;
    #pragma unroll
    for (int b = 0; b < 64; ++b)
      params[(size_t)b*PPS_ + off] = acc[b];
  }
}

// ---------------- decoder: 8 groups x 32 blocks x 8 waves; all-int8 streams
// R8 pipeline skeleton (wrap-issue in every HALF, no mid-loop drain, default
// block mapping) + R9 int8 payload (5-gld chunks: whh 4 + gru-int8 1).
__global__ __launch_bounds__(512, 2) void k_decoder(
    const float* __restrict__ inputs, const float* __restrict__ gru_Wih,
    const float* __restrict__ gru_bias,
    const signed char* __restrict__ whh_q, const float* __restrict__ scales,
    const signed char* __restrict__ gru_q, const float* __restrict__ scales_g,
    const float* __restrict__ params,
    unsigned short* __restrict__ h_buf, float* __restrict__ dec,
    float* __restrict__ out_states, unsigned int* __restrict__ bar)
{
  __shared__ __align__(16) unsigned short h_bf[8*1048];   // stride 2096 B
  __shared__ __align__(16) signed char h_q8[8*1040];      // stride 1040 B
  __shared__ __align__(16) char stg[8][2][5120];          // 80 KB
  __shared__ unsigned short wih_lds[8192];  // [s][i][c32] bf16
  __shared__ unsigned short gwih_lds[2048]; // [i][gate*32+c] bf16
  __shared__ float x_lds[256];
  __shared__ float gh_lds[1024];            // [w][sample][col16]
  __shared__ float mv_lds[256];             // [sample][col32]
  __shared__ float sc_lds[256];             // [w][kt] whh premult scale
  __shared__ float sgr_lds[128];            // [w][16kt] gru premult scale
  int tid = threadIdx.x;
  int g = blockIdx.x >> 5, bg = blockIdx.x & 31;   // default mapping (same-bg already co-XCD)
  int c0 = bg*32, gs = g*8;
  int w = tid >> 6, lane = tid & 63;
  int s_t = (tid >> 5) & 7, c_t = tid & 31;     // epilogue mapping (tid<256)
  int sg_t = gs + s_t, cg_t = c0 + c_t;
  float bh_r = 0.f, br_b = 0.f, bz_b = 0.f;
  if (tid < 256) {
    bh_r = params[(size_t)sg_t*PPS_ + cg_t];
    br_b = gru_bias[cg_t];
    bz_b = gru_bias[1024 + cg_t];
  }
  for (int idx = tid; idx < 2048; idx += 512) {
    int i = idx >> 6, gc = idx & 63;
    gwih_lds[idx] = f2b(gru_Wih[i*2048 + (gc>>5)*1024 + c0 + (gc&31)]);
  }
  for (int idx = tid; idx < 8192; idx += 512) {
    int s = idx >> 10, r = idx & 1023;
    wih_lds[idx] = f2b(params[(size_t)(gs+s)*PPS_ + 1024 + (r>>5)*1024 + c0 + (r&31)]);
  }
  if (lane < 32)
    sc_lds[w*32 + lane] = scales[(size_t)(gs+w)*1024 + lane*32 + bg] * (1.f/16129.f);
  int j_t = w >> 1;                              // gh tile 0..3
  int nt_j = (j_t < 2) ? (2*bg + j_t) : (64 + 2*bg + (j_t - 2));
  if (lane < 16)
    sgr_lds[w*16 + lane] = scales_g[nt_j*32 + (w&1)*16 + lane] * (1.f/16129.f);
  // wave-private stream bases (+ lane*16 for glds)
  const char* af0c = (const char*)whh_q + (size_t)((gs+w)*64 + 2*bg)*16384 + lane*16;
  const char* af1c = af0c + 16384;
  const char* gfc = (const char*)gru_q + ((size_t)nt_j*32 + (w&1)*16)*512 + lane*16;
  int ho_l = (lane>>4)<<3;
  int ghk0 = (w&1)*16;
  char* bufA = &stg[w][0][0];
  char* bufB = &stg[w][1][0];

  auto ISSUE = [&](char* bufp, int cc) {   // one 4-kt chunk: 5 x 1KB glds
    const char* a0 = af0c + (size_t)cc*2048;
    const char* a1 = af1c + (size_t)cc*2048;
    glds16(a0,        bufp);        glds16(a0 + 1024, bufp + 1024);
    glds16(a1,        bufp + 2048); glds16(a1 + 1024, bufp + 3072);
    glds16(gfc + (size_t)cc*1024, bufp + 4096);
  };
  f32x4 aghf, facc0, facc1;
  auto HALF = [&](char* bufp, int c) {     // consume chunk c, wrap-issue c+2
    asm volatile("s_waitcnt vmcnt(5)" ::: "memory");   // chunk c landed
    long a00 = *(const long*)(bufp + 0*512 + lane*8);
    long a01 = *(const long*)(bufp + 1*512 + lane*8);
    long a02 = *(const long*)(bufp + 2*512 + lane*8);
    long a03 = *(const long*)(bufp + 3*512 + lane*8);
    long a10 = *(const long*)(bufp + 2048 + 0*512 + lane*8);
    long a11 = *(const long*)(bufp + 2048 + 1*512 + lane*8);
    long a12 = *(const long*)(bufp + 2048 + 2*512 + lane*8);
    long a13 = *(const long*)(bufp + 2048 + 3*512 + lane*8);
    long qg0 = *(const long*)(bufp + 4096 + lane*8);
    long qg1 = *(const long*)(bufp + 4608 + lane*8);
    long hq0 = *(const long*)(h_q8 + w*1040 + (4*c+0)*32 + ho_l);
    long hq1 = *(const long*)(h_q8 + w*1040 + (4*c+1)*32 + ho_l);
    long hq2 = *(const long*)(h_q8 + w*1040 + (4*c+2)*32 + ho_l);
    long hq3 = *(const long*)(h_q8 + w*1040 + (4*c+3)*32 + ho_l);
    long haq0 = *(const long*)(h_q8 + (lane&15)*1040 + (ghk0 + 2*c)*32 + ho_l);
    long haq1 = *(const long*)(h_q8 + (lane&15)*1040 + (ghk0 + 2*c+1)*32 + ho_l);
    float s0 = sc_lds[w*32 + 4*c + 0];
    float s1 = sc_lds[w*32 + 4*c + 1];
    float s2 = sc_lds[w*32 + 4*c + 2];
    float s3 = sc_lds[w*32 + 4*c + 3];
    float g0 = sgr_lds[w*16 + 2*c], g1 = sgr_lds[w*16 + 2*c + 1];
    asm volatile("s_waitcnt lgkmcnt(0)" ::: "memory"); // all reads done
    __builtin_amdgcn_sched_barrier(0);
    ISSUE(bufp, (c + 2) & 7);              // wraps into next step's 0/1 at c=6,7
    i32x4 z4 = {0,0,0,0};
    i32x4 q;
    q = __builtin_amdgcn_mfma_i32_16x16x32_i8(a00, hq0, z4, 0,0,0);
    #pragma unroll
    for (int e = 0; e < 4; ++e) facc0[e] += (float)q[e]*s0;
    q = __builtin_amdgcn_mfma_i32_16x16x32_i8(a01, hq1, z4, 0,0,0);
    #pragma unroll
    for (int e = 0; e < 4; ++e) facc0[e] += (float)q[e]*s1;
    q = __builtin_amdgcn_mfma_i32_16x16x32_i8(a02, hq2, z4, 0,0,0);
    #pragma unroll
    for (int e = 0; e < 4; ++e) facc0[e] += (float)q[e]*s2;
    q = __builtin_amdgcn_mfma_i32_16x16x32_i8(a03, hq3, z4, 0,0,0);
    #pragma unroll
    for (int e = 0; e < 4; ++e) facc0[e] += (float)q[e]*s3;
    q = __builtin_amdgcn_mfma_i32_16x16x32_i8(a10, hq0, z4, 0,0,0);
    #pragma unroll
    for (int e = 0; e < 4; ++e) facc1[e] += (float)q[e]*s0;
    q = __builtin_amdgcn_mfma_i32_16x16x32_i8(a11, hq1, z4, 0,0,0);
    #pragma unroll
    for (int e = 0; e < 4; ++e) facc1[e] += (float)q[e]*s1;
    q = __builtin_amdgcn_mfma_i32_16x16x32_i8(a12, hq2, z4, 0,0,0);
    #pragma unroll
    for (int e = 0; e < 4; ++e) facc1[e] += (float)q[e]*s2;
    q = __builtin_amdgcn_mfma_i32_16x16x32_i8(a13, hq3, z4, 0,0,0);
    #pragma unroll
    for (int e = 0; e < 4; ++e) facc1[e] += (float)q[e]*s3;
    q = __builtin_amdgcn_mfma_i32_16x16x32_i8(haq0, qg0, z4, 0,0,0);
    #pragma unroll
    for (int e = 0; e < 4; ++e) aghf[e] += (float)q[e]*g0;
    q = __builtin_amdgcn_mfma_i32_16x16x32_i8(haq1, qg1, z4, 0,0,0);
    #pragma unroll
    for (int e = 0; e < 4; ++e) aghf[e] += (float)q[e]*g1;
  };

  __syncthreads();
  ISSUE(bufA, 0); ISSUE(bufB, 1);   // prologue: 2 chunks in flight
  for (int t = 0; t < 128; ++t) {
    int rb = t & 1;
    if (t > 0 && tid == 0) {
      while (__hip_atomic_load(&bar[(g<<7)+(t-1)], __ATOMIC_ACQUIRE, __HIP_MEMORY_SCOPE_AGENT) < 32u)
        __builtin_amdgcn_s_sleep(1);
    }
    __builtin_amdgcn_s_barrier();
    { // stage h: wave w stages its sample (2 KB)
      const char* hs = (const char*)(h_buf + (size_t)rb*B_*HD_ + (size_t)(gs + w)*HD_) + lane*16;
      glds16(hs,        &h_bf[w*1048]);
      glds16(hs + 1024, &h_bf[w*1048 + 512]);
    }
    if (tid < 256) x_lds[tid] = inputs[((size_t)sg_t*T_ + t)*DIN_ + c_t];
    asm volatile("s_waitcnt vmcnt(0)" ::: "memory");   // h + x + prefetch landed
    __builtin_amdgcn_s_barrier();
    { // wave-local: quantize own sample's h to int8 (scale 127, |h|<=1)
      i32x4 pk;
      #pragma unroll
      for (int hh = 0; hh < 2; ++hh) {
        bf16x8 hv = *(const bf16x8*)(&h_bf[w*1048 + lane*16 + hh*8]);
        int lo = 0, hi2 = 0;
        #pragma unroll
        for (int e = 0; e < 4; ++e) {
          int q = (int)rintf(b2f((unsigned short)hv[e]) * 127.f);
          lo |= (q & 255) << (8*e);
        }
        #pragma unroll
        for (int e = 0; e < 4; ++e) {
          int q = (int)rintf(b2f((unsigned short)hv[4+e]) * 127.f);
          hi2 |= (q & 255) << (8*e);
        }
        pk[2*hh] = lo; pk[2*hh+1] = hi2;
      }
      *(i32x4*)(h_q8 + w*1040 + lane*16) = pk;
    }
    asm volatile("s_waitcnt lgkmcnt(0)" ::: "memory");
    __builtin_amdgcn_s_barrier();   // h_q8 all rows visible (gh reads cross-wave)
    aghf = (f32x4){0,0,0,0}; facc0 = (f32x4){0,0,0,0}; facc1 = (f32x4){0,0,0,0};
    #pragma unroll 1
    for (int i2 = 0; i2 < 4; ++i2) {   // 8 chunks; HALF 6,7 wrap-issue next step
      HALF(bufA, 2*i2);
      HALF(bufB, 2*i2 + 1);
    }
    // exchange partials
    if (lane < 32) {          // gh D rows 0..7 = samples, cols = lane&15
      #pragma unroll
      for (int i = 0; i < 4; ++i)
        gh_lds[w*128 + ((lane>>4)*4 + i)*16 + (lane&15)] = aghf[i];
    }
    if ((lane & 15) == 0) {   // mv valid at n=0; rows = col-in-tile
      int cb = (lane>>4)*4;
      #pragma unroll
      for (int i = 0; i < 4; ++i) {
        mv_lds[w*32 + cb + i]      = facc0[i];
        mv_lds[w*32 + 16 + cb + i] = facc1[i];
      }
    }
    asm volatile("s_waitcnt lgkmcnt(0)" ::: "memory");
    __builtin_amdgcn_s_barrier();
    if (tid < 256) {
      int jr = c_t >> 4, cl16 = c_t & 15;
      float ghr = gh_lds[(2*jr)*128   + s_t*16 + cl16] + gh_lds[(2*jr+1)*128 + s_t*16 + cl16];
      float ghz = gh_lds[(4+2*jr)*128 + s_t*16 + cl16] + gh_lds[(5+2*jr)*128 + s_t*16 + cl16];
      float gxr = 0.f, gxz = 0.f, ex = 0.f;
      #pragma unroll 8
      for (int i = 0; i < 32; ++i) {
        float xv = x_lds[s_t*32 + i];
        gxr += xv * b2f(gwih_lds[i*64 + c_t]);
        gxz += xv * b2f(gwih_lds[i*64 + 32 + c_t]);
        ex  += xv * b2f(wih_lds[s_t*1024 + i*32 + c_t]);
      }
      float r = sigm_(gxr + ghr + br_b);
      float z = sigm_(gxz + ghz + bz_b);
      float eta = tanh_(ex + bh_r + r * mv_lds[s_t*32 + c_t]);
      float ho_ = b2f(h_bf[s_t*1048 + c0 + c_t]);
      float hn = z*ho_ + (1.f - z)*eta;
      dec[((size_t)sg_t*T_ + t)*HD_ + cg_t] = hn;
      h_buf[(size_t)(rb^1)*B_*HD_ + (size_t)sg_t*HD_ + cg_t] = f2b(hn);
      if (t == 127) out_states[(size_t)sg_t*HD_ + cg_t] = hn;
    }
    asm volatile("s_waitcnt vmcnt(0)" ::: "memory");  // stores (+wrap prefetch) drained
    __builtin_amdgcn_s_barrier();
    if (t < 127 && tid == 0)
      __hip_atomic_fetch_add(&bar[(g<<7)+t], 1u, __ATOMIC_ACQ_REL, __HIP_MEMORY_SCOPE_AGENT);
  }
}

// ---------------- yhats = dec @ C_b + concat(x, x @ D_b) ----------------
__global__ __launch_bounds__(256) void k_yhats(
    const float* __restrict__ dec, const float* __restrict__ inputs,
    const float* __restrict__ params, float* __restrict__ out_y)
{
  __shared__ __align__(16) float dsm[8*1024];
  __shared__ float xr[8*32];
  int blk = blockIdx.x, tid = threadIdx.x;
  int b = blk >> 4, t8 = (blk & 15) * 8;
  const float* prm = params + (size_t)b*PPS_;
  const float* C = prm + 33792;
  const float* D = prm + 99328;
  #pragma unroll
  for (int j = 0; j < 8; ++j) {
    int ch = j*256 + tid;
    *(f32x4*)(&dsm[ch*4]) = *(const f32x4*)(dec + ((size_t)b*T_ + t8)*HD_ + ch*4);
  }
  {
    int tl = tid >> 5, i = tid & 31;
    xr[tl*32 + i] = inputs[((size_t)b*T_ + t8 + tl)*DIN_ + i];
    xr[(tl+4)*32 + i] = inputs[((size_t)b*T_ + t8 + tl + 4)*DIN_ + i];
  }
  __syncthreads();
  int o = tid & 63;
  int tl0 = (tid >> 6) * 2;
  float a0 = 0.f, a1 = 0.f;
  #pragma unroll 4
  for (int h = 0; h < 1024; ++h) {
    float cv = C[h*64 + o];
    a0 += dsm[tl0*1024 + h] * cv;
    a1 += dsm[(tl0+1)*1024 + h] * cv;
  }
  float r0, r1;
  if (o < 32) {
    r0 = xr[tl0*32 + o];
    r1 = xr[(tl0+1)*32 + o];
  } else {
    r0 = 0.f; r1 = 0.f;
    #pragma unroll 8
    for (int i = 0; i < 32; ++i) {
      float dv = D[i*32 + (o-32)];
      r0 += xr[tl0*32 + i] * dv;
      r1 += xr[(tl0+1)*32 + i] * dv;
    }
  }
  out_y[((size_t)b*T_ + t8 + tl0)*DOUT_ + o]     = a0 + r0;
  out_y[((size_t)b*T_ + t8 + tl0 + 1)*DOUT_ + o] = a1 + r1;
}

extern "C" void kernel_launch(void* const* d_in, const int* in_sizes, int n_in,
                              void* d_out, int out_size, void* d_ws, size_t ws_size,
                              hipStream_t stream)
{
  const float* inputs  = (const float*)d_in[0];
  const float* outputs = (const float*)d_in[1];
  const float* eps     = (const float*)d_in[2];
  const float* state   = (const float*)d_in[3];
  const float* enc_Wih = (const float*)d_in[4];
  const float* enc_Whh = (const float*)d_in[5];
  const float* enc_bih = (const float*)d_in[6];
  const float* enc_bhh = (const float*)d_in[7];
  const float* to_mu   = (const float*)d_in[8];
  const float* to_ls   = (const float*)d_in[9];
  const float* to_lsb  = (const float*)d_in[10];
  const float* psi_W1  = (const float*)d_in[11];
  const float* psi_b1  = (const float*)d_in[12];
  const float* psi_W2  = (const float*)d_in[13];
  const float* psi_b2  = (const float*)d_in[14];
  const float* psi_W3  = (const float*)d_in[15];
  const float* psi_b3  = (const float*)d_in[16];
  const float* gru_Wih = (const float*)d_in[17];
  const float* gru_Whh = (const float*)d_in[18];
  const float* gru_bias= (const float*)d_in[19];
  float* out    = (float*)d_out;
  float* out_y  = out;
  float* out_mu = out + 524288;
  float* out_ls = out + 525056;
  float* out_st = out + 525824;

  if (ws_size < 130000000) return;  // fail loudly rather than corrupt
  char* ws = (char*)d_ws;
  size_t off = 0;
  auto alloc = [&](size_t bytes)->char*{ char* p = ws + off; off += (bytes + 255) & ~(size_t)255; return p; };
  signed char* whh_q      = (signed char*)alloc(67108864);
  float* scales           = (float*)alloc(262144);
  unsigned short* encW_f  = (unsigned short*)alloc(1572864);
  unsigned short* encI_f  = (unsigned short*)alloc(196608);
  signed char* gru_q      = (signed char*)alloc(2097152);
  float* scales_g         = (float*)alloc(16384);
  float* params           = (float*)alloc(25690112);
  float* h_enc            = (float*)alloc(131072);
  float* z_lat            = (float*)alloc(3072);
  float* hidden_T         = (float*)alloc(16384);
  unsigned short* h_buf_e = (unsigned short*)alloc(131072);
  unsigned short* h_buf_d = (unsigned short*)alloc(262144);
  float* dec              = (float*)alloc(33554432);
  unsigned int* bar_e     = (unsigned int*)alloc(8192);
  unsigned int* bar_d     = (unsigned int*)alloc(8192);

  hipMemsetAsync(bar_e, 0, 8192, stream);
  hipMemsetAsync(bar_d, 0, 8192, stream);
  hipMemsetAsync(h_buf_e, 0, 131072, stream);

  k_prep<<<5888, 512, 0, stream>>>(enc_Whh, enc_Wih, gru_Whh, state, encW_f, encI_f, gru_q, scales_g, h_buf_d);
  k_encoder<<<512, 128, 0, stream>>>(outputs, enc_bih, enc_bhh, encW_f, encI_f, h_buf_e, h_enc, bar_e);
  k_latent<<<64, 64, 0, stream>>>(h_enc, to_mu, to_ls, to_lsb, eps, out_mu, out_ls, z_lat);
  k_hidden<<<64, 512, 0, stream>>>(z_lat, psi_W1, psi_b1, psi_W2, psi_b2, hidden_T);
  k_psi<<<2146, 1024, 0, stream>>>(hidden_T, psi_W3, psi_b3, whh_q, scales, params);
  k_decoder<<<256, 512, 0, stream>>>(inputs, gru_Wih, gru_bias, whh_q, scales, gru_q, scales_g, params, h_buf_d, dec, out_st, bar_d);
  k_yhats<<<1024, 256, 0, stream>>>(dec, inputs, params, out_y);
}

// Round 11
// 4328.942 us; speedup vs baseline: 1.2885x; 1.2254x over previous
//
#include <hip/hip_runtime.h>
#include <stdint.h>

#define B_ 64
#define T_ 128
#define DIN_ 32
#define DOUT_ 64
#define HE_ 512
#define HD_ 1024
#define NPSI_ 1148928
#define PPS_ 100352   // per-sample non-Whh params (floats): bh[1024] Wih[32*1024] C[1024*64] D[32*32]

typedef short bf16x8 __attribute__((ext_vector_type(8)));
typedef float f32x4 __attribute__((ext_vector_type(4)));
typedef int   i32x4 __attribute__((ext_vector_type(4)));

__device__ __forceinline__ unsigned short f2b(float f){
  unsigned u = __float_as_uint(f);
  u += 0x7fffu + ((u>>16)&1u);      // round-to-nearest-even bf16
  return (unsigned short)(u>>16);
}
__device__ __forceinline__ float b2f(unsigned short s){
  return __uint_as_float(((unsigned)s)<<16);
}
__device__ __forceinline__ float sigm_(float x){
  float e = __expf(-x);
  return 1.f/(1.f+e);
}
__device__ __forceinline__ float tanh_(float x){
  float e = __expf(2.f*x);
  return 1.f - 2.f/(e+1.f);         // safe at +-inf
}
// async global->LDS: 64 lanes x 16 B = 1 KB; LDS dest wave-uniform, global
// src per-lane. Counts in vmcnt.
__device__ __forceinline__ void glds16(const void* g, void* l) {
  __builtin_amdgcn_global_load_lds(
      (const __attribute__((address_space(1))) unsigned int*)g,
      (__attribute__((address_space(3))) unsigned int*)l, 16, 0, 0);
}

// ---------------- prep: bf16 frag swizzles, gru int8 quant, h_dec init ------
__global__ __launch_bounds__(512) void k_prep(
    const float* __restrict__ enc_Whh, const float* __restrict__ enc_Wih,
    const float* __restrict__ gru_Whh, const float* __restrict__ state,
    unsigned short* __restrict__ encW_f, unsigned short* __restrict__ encI_f,
    signed char* __restrict__ gru_q, float* __restrict__ scales_g,
    unsigned short* __restrict__ h_dec)
{
  __shared__ unsigned gmax_s;
  __shared__ __align__(16) signed char gq[512];
  int blk = blockIdx.x, tid = threadIdx.x;
  if (blk < 1536) {                       // enc_Whh: gh = h @ Whh^T -> B[k][n]=Whh[n][k]
    int nt = blk >> 4, kt = blk & 15;
    int c = tid >> 5, k = tid & 31;
    float v = enc_Whh[(size_t)(nt*16 + c)*HE_ + kt*32 + k];
    int l = c + ((k>>3)<<4), jj = k & 7;
    encW_f[(size_t)(nt*16 + kt)*512 + l*8 + jj] = f2b(v);
  } else if (blk < 1728) {                // enc_Wih: B[k][n]=Wih[n][k]
    int f = blk - 1536; int nt = f >> 1, kt = f & 1;
    int c = tid >> 5, k = tid & 31;
    float v = enc_Wih[(size_t)(nt*16 + c)*DOUT_ + kt*32 + k];
    int l = c + ((k>>3)<<4), jj = k & 7;
    encI_f[(size_t)(nt*2 + kt)*512 + l*8 + jj] = f2b(v);
  } else if (blk < 5824) {                // gru_Whh -> int8 frags + per-tile scale
    int f = blk - 1728; int nt = f >> 5, kt = f & 31;
    int k = tid >> 4, c = tid & 15;
    float v = gru_Whh[(size_t)(kt*32 + k)*2048 + nt*16 + c];
    int l = c + ((k>>3)<<4), jj = k & 7;
    if (tid == 0) gmax_s = 0;
    __syncthreads();
    float av = fabsf(v);
    #pragma unroll
    for (int d = 1; d < 64; d <<= 1) av = fmaxf(av, __shfl_xor(av, d));
    if ((tid & 63) == 0) atomicMax(&gmax_s, __float_as_uint(av));
    __syncthreads();
    float m = __uint_as_float(gmax_s);
    float inv = (m > 0.f) ? (127.f/m) : 0.f;
    gq[l*8 + jj] = (signed char)(int)rintf(v*inv);
    __syncthreads();
    if (tid < 32)
      *(i32x4*)(gru_q + (size_t)(nt*32 + kt)*512 + tid*16) = *(const i32x4*)(&gq[tid*16]);
    if (tid == 0) scales_g[nt*32 + kt] = m;
  } else {                                // h_dec buf0 init from `state`
    int b = blk - 5824;
    h_dec[(size_t)b*HD_ + tid]       = f2b(state[(size_t)b*HD_ + tid]);
    h_dec[(size_t)b*HD_ + 512 + tid] = f2b(state[(size_t)b*HD_ + 512 + tid]);
  }
}

// ---------------- encoder: 8 groups x 32 blocks x 2 waves (K-split) ----------
__global__ __launch_bounds__(128) void k_encoder(
    const float* __restrict__ outputs, const float* __restrict__ bih, const float* __restrict__ bhh,
    const unsigned short* __restrict__ encW_f, const unsigned short* __restrict__ encI_f,
    unsigned short* __restrict__ h_buf, float* __restrict__ h_enc, unsigned int* __restrict__ bar)
{
  __shared__ __align__(16) unsigned short h_bf[16*520];   // [16][512+8pad] bf16
  __shared__ __align__(16) unsigned short xa[16*72];      // [16][64+8pad]
  __shared__ float part[64*16];                           // wave1 partial accs
  int tid = threadIdx.x, wv = tid >> 6, lane = tid & 63;
  int g = blockIdx.x >> 5, bg = blockIdx.x & 31;
  int c0 = bg*16, gs = g*8;
  for (int i = tid; i < 16*520; i += 128) h_bf[i] = 0;
  for (int i = tid; i < 16*72; i += 128) xa[i] = 0;
  int cl = c0 + (lane & 15);
  float br_b = bih[cl] + bhh[cl];
  float bz_b = bih[512+cl] + bhh[512+cl];
  float bin_b = bih[1024+cl];
  float bhn_b = bhh[1024+cl];
  float hreg[4] = {0.f,0.f,0.f,0.f};
  int row = (lane>>4)<<2;
  int nt_r = bg, nt_z = 32+bg, nt_n = 64+bg;
  __syncthreads();
  for (int t = 0; t < 128; ++t) {
    int rb = t & 1;
    if (t > 0) {
      if (tid == 0) {
        while (__hip_atomic_load(&bar[(g<<7)+(t-1)], __ATOMIC_ACQUIRE, __HIP_MEMORY_SCOPE_AGENT) < 32u)
          __builtin_amdgcn_s_sleep(2);
      }
      __syncthreads();
    }
    { // reload h (8 samples x 512 bf16) + x_t
      const unsigned short* src = h_buf + (size_t)rb*B_*HE_ + (size_t)gs*HE_;
      #pragma unroll
      for (int j = 0; j < 4; ++j) {
        int chunk = j*128 + tid;
        bf16x8 v = *(const bf16x8*)(src + chunk*8);
        int s = chunk >> 6, col = (chunk & 63) * 8;
        *(bf16x8*)(&h_bf[s*520 + col]) = v;
      }
      #pragma unroll
      for (int j = 0; j < 4; ++j) {
        int e = j*128 + tid;
        int s = e >> 6, d = e & 63;
        xa[s*72 + d] = f2b(outputs[((size_t)(gs+s)*T_ + t)*DOUT_ + d]);
      }
    }
    __syncthreads();
    f32x4 accr = {0,0,0,0}, accz = {0,0,0,0}, accn = {0,0,0,0}, accgi = {0,0,0,0};
    { // gi = x @ Wih^T, kt = wv
      bf16x8 a = *(const bf16x8*)(&xa[(lane&15)*72 + wv*32 + ((lane>>4)<<3)]);
      bf16x8 b0 = *(const bf16x8*)(encI_f + (size_t)(nt_r*2+wv)*512 + lane*8);
      bf16x8 b1 = *(const bf16x8*)(encI_f + (size_t)(nt_z*2+wv)*512 + lane*8);
      bf16x8 b2 = *(const bf16x8*)(encI_f + (size_t)(nt_n*2+wv)*512 + lane*8);
      accr  = __builtin_amdgcn_mfma_f32_16x16x32_bf16(a, b0, accr, 0,0,0);
      accz  = __builtin_amdgcn_mfma_f32_16x16x32_bf16(a, b1, accz, 0,0,0);
      accgi = __builtin_amdgcn_mfma_f32_16x16x32_bf16(a, b2, accgi, 0,0,0);
    }
    #pragma unroll
    for (int kk = 0; kk < 8; ++kk) {      // gh = h @ Whh^T, K-half per wave
      int kt = wv*8 + kk;
      bf16x8 a = *(const bf16x8*)(&h_bf[(lane&15)*520 + kt*32 + ((lane>>4)<<3)]);
      bf16x8 b0 = *(const bf16x8*)(encW_f + (size_t)(nt_r*16+kt)*512 + lane*8);
      bf16x8 b1 = *(const bf16x8*)(encW_f + (size_t)(nt_z*16+kt)*512 + lane*8);
      bf16x8 b2 = *(const bf16x8*)(encW_f + (size_t)(nt_n*16+kt)*512 + lane*8);
      accr = __builtin_amdgcn_mfma_f32_16x16x32_bf16(a, b0, accr, 0,0,0);
      accz = __builtin_amdgcn_mfma_f32_16x16x32_bf16(a, b1, accz, 0,0,0);
      accn = __builtin_amdgcn_mfma_f32_16x16x32_bf16(a, b2, accn, 0,0,0);
    }
    if (wv == 1) {
      #pragma unroll
      for (int i = 0; i < 4; ++i) {
        part[lane*16 + i]      = accr[i];
        part[lane*16 + 4 + i]  = accz[i];
        part[lane*16 + 8 + i]  = accn[i];
        part[lane*16 + 12 + i] = accgi[i];
      }
    }
    __syncthreads();
    if (wv == 0 && row < 8) {
      unsigned short* dst = h_buf + (size_t)(rb^1)*B_*HE_;
      #pragma unroll
      for (int i = 0; i < 4; ++i) {
        int s = row + i;
        float ar  = accr[i]  + part[lane*16 + i];
        float az  = accz[i]  + part[lane*16 + 4 + i];
        float an  = accn[i]  + part[lane*16 + 8 + i];
        float agi = accgi[i] + part[lane*16 + 12 + i];
        float r = sigm_(ar + br_b);
        float z = sigm_(az + bz_b);
        float n = tanh_(agi + bin_b + r*(an + bhn_b));
        float hn = (1.f - z)*n + z*hreg[i];
        hreg[i] = hn;
        dst[(size_t)(gs+s)*HE_ + cl] = f2b(hn);
        if (t == 127) h_enc[(size_t)(gs+s)*HE_ + cl] = hn;
      }
    }
    __syncthreads();
    if (tid == 0)
      __hip_atomic_fetch_add(&bar[(g<<7)+t], 1u, __ATOMIC_ACQ_REL, __HIP_MEMORY_SCOPE_AGENT);
  }
}

// ---------------- latent: mu / logstd / z ----------------
__global__ __launch_bounds__(64) void k_latent(
    const float* __restrict__ h_enc, const float* __restrict__ to_mu,
    const float* __restrict__ to_ls, const float* __restrict__ ls_bias,
    const float* __restrict__ eps, float* __restrict__ out_mu,
    float* __restrict__ out_ls, float* __restrict__ z_lat)
{
  __shared__ float hb[512];
  int b = blockIdx.x, tid = threadIdx.x;
  #pragma unroll
  for (int j = 0; j < 8; ++j) hb[j*64 + tid] = h_enc[(size_t)b*HE_ + j*64 + tid];
  __syncthreads();
  if (tid < 12) {
    float m = 0.f, s = 0.f;
    #pragma unroll 8
    for (int k = 0; k < 512; ++k) {
      float h = hb[k];
      m += h * to_mu[k*12 + tid];
      s += h * to_ls[k*12 + tid];
    }
    s += ls_bias[tid];
    out_mu[b*12 + tid] = m;
    out_ls[b*12 + tid] = s;
    z_lat[b*12 + tid] = m + eps[b*12 + tid] * __expf(s);
  }
}

// ---------------- hidden = tanh(z@W1+b1)@W2+b2, stored transposed [64k][64b] ----
__global__ __launch_bounds__(512) void k_hidden(
    const float* __restrict__ z_lat, const float* __restrict__ W1, const float* __restrict__ b1,
    const float* __restrict__ W2, const float* __restrict__ b2, float* __restrict__ hidden_T)
{
  __shared__ float zl[12];
  __shared__ float a[512];
  int b = blockIdx.x, tid = threadIdx.x;
  if (tid < 12) zl[tid] = z_lat[b*12 + tid];
  __syncthreads();
  float acc = b1[tid];
  #pragma unroll
  for (int k = 0; k < 12; ++k) acc += zl[k] * W1[k*512 + tid];
  a[tid] = tanh_(acc);
  __syncthreads();
  if (tid < 64) {
    float h = b2[tid];
    #pragma unroll 8
    for (int j = 0; j < 512; ++j) h += a[j] * W2[j*64 + tid];
    hidden_T[tid*64 + b] = h;
  }
}

// ---------------- psi expansion: whh -> int8 frags (32 samples/block) --------
__global__ __launch_bounds__(1024) void k_psi(
    const float* __restrict__ hidden_T, const float* __restrict__ W3, const float* __restrict__ b3,
    signed char* __restrict__ whh_q, float* __restrict__ scales, float* __restrict__ params)
{
  __shared__ float hid[64*64];
  __shared__ unsigned lmax[32];
  __shared__ __align__(16) signed char qtile[32*1024];
  int tid = threadIdx.x, blk = blockIdx.x;
  if (tid < 32) lmax[tid] = 0;
  #pragma unroll
  for (int j = 0; j < 4; ++j) hid[j*1024 + tid] = hidden_T[j*1024 + tid];
  __syncthreads();
  bool is_whh = blk < 2048;
  if (is_whh) {
    int kt = blk >> 6, cp = (blk >> 1) & 31, bh = blk & 1;
    int i_loc = tid >> 5, c_loc = tid & 31;
    size_t j = (size_t)(kt*32 + i_loc)*1024 + cp*32 + c_loc;
    float bv = b3[j];
    float acc[32];
    #pragma unroll
    for (int b = 0; b < 32; ++b) acc[b] = bv;
    for (int k = 0; k < 64; ++k) {
      float wv = W3[(size_t)k*NPSI_ + j];
      #pragma unroll
      for (int bq = 0; bq < 8; ++bq) {
        f32x4 h4 = *(const f32x4*)(&hid[k*64 + bh*32 + bq*4]);
        acc[bq*4+0] += wv * h4[0];
        acc[bq*4+1] += wv * h4[1];
        acc[bq*4+2] += wv * h4[2];
        acc[bq*4+3] += wv * h4[3];
      }
    }
    #pragma unroll
    for (int b = 0; b < 32; ++b) {
      float av = fabsf(acc[b]);
      #pragma unroll
      for (int d = 1; d < 64; d <<= 1) av = fmaxf(av, __shfl_xor(av, d));
      if ((tid & 63) == 0) atomicMax(&lmax[b], __float_as_uint(av));
    }
    __syncthreads();
    int l = (c_loc & 15) + (((i_loc>>3)&3)<<4);
    int jj = i_loc & 7;
    int base_lds = ((c_loc>>4)<<9) + l*8 + jj;
    #pragma unroll
    for (int b = 0; b < 32; ++b) {
      float m = __uint_as_float(lmax[b]);
      float inv = (m > 0.f) ? (127.f/m) : 0.f;
      qtile[b*1024 + base_lds] = (signed char)(int)rintf(acc[b]*inv);
    }
    __syncthreads();
    #pragma unroll
    for (int it = 0; it < 2; ++it) {
      int qid = it*1024 + tid;
      int b = qid >> 6, c64 = qid & 63;
      i32x4 v = *(const i32x4*)(&qtile[b*1024 + c64*16]);
      size_t goff = (size_t)(bh*32 + b)*1048576
                  + (size_t)((2*cp + (c64>>5))*32 + kt)*512 + (c64&31)*16;
      *(i32x4*)(whh_q + goff) = v;
    }
    if (tid < 32)
      scales[(size_t)(bh*32 + tid)*1024 + kt*32 + cp] = __uint_as_float(lmax[tid]);
  } else {
    size_t j = (size_t)1048576 + (size_t)(blk - 2048)*1024 + tid;
    float bv = b3[j];
    float acc[64];
    #pragma unroll
    for (int b = 0; b < 64; ++b) acc[b] = bv;
    for (int k = 0; k < 64; ++k) {
      float wv = W3[(size_t)k*NPSI_ + j];
      #pragma unroll
      for (int bq = 0; bq < 16; ++bq) {
        f32x4 h4 = *(const f32x4*)(&hid[k*64 + bq*4]);
        acc[bq*4+0] += wv * h4[0];
        acc[bq*4+1] += wv * h4[1];
        acc[bq*4+2] += wv * h4[2];
        acc[bq*4+3] += wv * h4[3];
      }
    }
    size_t off = j - 1048576;
    #pragma unroll
    for (int b = 0; b < 64; ++b)
      params[(size_t)b*PPS_ + off] = acc[b];
  }
}

// ---------------- decoder: 8 groups x 32 blocks x 8 waves; all-int8 streams
// R8 skeleton, 4 barriers/step: wave w quantizes ITS OWN staged h row right
// after vmcnt(0) (no cross-wave dep), so one barrier publishes h_bf AND h_q8.
__global__ __launch_bounds__(512, 2) void k_decoder(
    const float* __restrict__ inputs, const float* __restrict__ gru_Wih,
    const float* __restrict__ gru_bias,
    const signed char* __restrict__ whh_q, const float* __restrict__ scales,
    const signed char* __restrict__ gru_q, const float* __restrict__ scales_g,
    const float* __restrict__ params,
    unsigned short* __restrict__ h_buf, float* __restrict__ dec,
    float* __restrict__ out_states, unsigned int* __restrict__ bar)
{
  __shared__ __align__(16) unsigned short h_bf[8*1048];   // stride 2096 B
  __shared__ __align__(16) signed char h_q8[8*1040];      // stride 1040 B
  __shared__ __align__(16) char stg[8][2][5120];          // 80 KB
  __shared__ unsigned short wih_lds[8192];  // [s][i][c32] bf16
  __shared__ unsigned short gwih_lds[2048]; // [i][gate*32+c] bf16
  __shared__ float x_lds[256];
  __shared__ float gh_lds[1024];            // [w][sample][col16]
  __shared__ float mv_lds[256];             // [sample][col32]
  __shared__ float sc_lds[256];             // [w][kt] whh premult scale
  __shared__ float sgr_lds[128];            // [w][16kt] gru premult scale
  int tid = threadIdx.x;
  int g = blockIdx.x >> 5, bg = blockIdx.x & 31;   // same-bg already co-XCD under round-robin
  int c0 = bg*32, gs = g*8;
  int w = tid >> 6, lane = tid & 63;
  int s_t = (tid >> 5) & 7, c_t = tid & 31;     // epilogue mapping (tid<256)
  int sg_t = gs + s_t, cg_t = c0 + c_t;
  float bh_r = 0.f, br_b = 0.f, bz_b = 0.f;
  if (tid < 256) {
    bh_r = params[(size_t)sg_t*PPS_ + cg_t];
    br_b = gru_bias[cg_t];
    bz_b = gru_bias[1024 + cg_t];
  }
  for (int idx = tid; idx < 2048; idx += 512) {
    int i = idx >> 6, gc = idx & 63;
    gwih_lds[idx] = f2b(gru_Wih[i*2048 + (gc>>5)*1024 + c0 + (gc&31)]);
  }
  for (int idx = tid; idx < 8192; idx += 512) {
    int s = idx >> 10, r = idx & 1023;
    wih_lds[idx] = f2b(params[(size_t)(gs+s)*PPS_ + 1024 + (r>>5)*1024 + c0 + (r&31)]);
  }
  if (lane < 32)
    sc_lds[w*32 + lane] = scales[(size_t)(gs+w)*1024 + lane*32 + bg] * (1.f/16129.f);
  int j_t = w >> 1;                              // gh tile 0..3
  int nt_j = (j_t < 2) ? (2*bg + j_t) : (64 + 2*bg + (j_t - 2));
  if (lane < 16)
    sgr_lds[w*16 + lane] = scales_g[nt_j*32 + (w&1)*16 + lane] * (1.f/16129.f);
  // wave-private stream bases (+ lane*16 for glds)
  const char* af0c = (const char*)whh_q + (size_t)((gs+w)*64 + 2*bg)*16384 + lane*16;
  const char* af1c = af0c + 16384;
  const char* gfc = (const char*)gru_q + ((size_t)nt_j*32 + (w&1)*16)*512 + lane*16;
  int ho_l = (lane>>4)<<3;
  int ghk0 = (w&1)*16;
  char* bufA = &stg[w][0][0];
  char* bufB = &stg[w][1][0];

  auto ISSUE = [&](char* bufp, int cc) {   // one 4-kt chunk: 5 x 1KB glds
    const char* a0 = af0c + (size_t)cc*2048;
    const char* a1 = af1c + (size_t)cc*2048;
    glds16(a0,        bufp);        glds16(a0 + 1024, bufp + 1024);
    glds16(a1,        bufp + 2048); glds16(a1 + 1024, bufp + 3072);
    glds16(gfc + (size_t)cc*1024, bufp + 4096);
  };
  f32x4 aghf, facc0, facc1;
  auto HALF = [&](char* bufp, int c) {     // consume chunk c, wrap-issue c+2
    asm volatile("s_waitcnt vmcnt(5)" ::: "memory");   // chunk c landed
    long a00 = *(const long*)(bufp + 0*512 + lane*8);
    long a01 = *(const long*)(bufp + 1*512 + lane*8);
    long a02 = *(const long*)(bufp + 2*512 + lane*8);
    long a03 = *(const long*)(bufp + 3*512 + lane*8);
    long a10 = *(const long*)(bufp + 2048 + 0*512 + lane*8);
    long a11 = *(const long*)(bufp + 2048 + 1*512 + lane*8);
    long a12 = *(const long*)(bufp + 2048 + 2*512 + lane*8);
    long a13 = *(const long*)(bufp + 2048 + 3*512 + lane*8);
    long qg0 = *(const long*)(bufp + 4096 + lane*8);
    long qg1 = *(const long*)(bufp + 4608 + lane*8);
    long hq0 = *(const long*)(h_q8 + w*1040 + (4*c+0)*32 + ho_l);
    long hq1 = *(const long*)(h_q8 + w*1040 + (4*c+1)*32 + ho_l);
    long hq2 = *(const long*)(h_q8 + w*1040 + (4*c+2)*32 + ho_l);
    long hq3 = *(const long*)(h_q8 + w*1040 + (4*c+3)*32 + ho_l);
    long haq0 = *(const long*)(h_q8 + (lane&15)*1040 + (ghk0 + 2*c)*32 + ho_l);
    long haq1 = *(const long*)(h_q8 + (lane&15)*1040 + (ghk0 + 2*c+1)*32 + ho_l);
    float s0 = sc_lds[w*32 + 4*c + 0];
    float s1 = sc_lds[w*32 + 4*c + 1];
    float s2 = sc_lds[w*32 + 4*c + 2];
    float s3 = sc_lds[w*32 + 4*c + 3];
    float g0 = sgr_lds[w*16 + 2*c], g1 = sgr_lds[w*16 + 2*c + 1];
    asm volatile("s_waitcnt lgkmcnt(0)" ::: "memory"); // all reads done
    __builtin_amdgcn_sched_barrier(0);
    ISSUE(bufp, (c + 2) & 7);              // wraps into next step's 0/1 at c=6,7
    i32x4 z4 = {0,0,0,0};
    i32x4 q;
    q = __builtin_amdgcn_mfma_i32_16x16x32_i8(a00, hq0, z4, 0,0,0);
    #pragma unroll
    for (int e = 0; e < 4; ++e) facc0[e] += (float)q[e]*s0;
    q = __builtin_amdgcn_mfma_i32_16x16x32_i8(a01, hq1, z4, 0,0,0);
    #pragma unroll
    for (int e = 0; e < 4; ++e) facc0[e] += (float)q[e]*s1;
    q = __builtin_amdgcn_mfma_i32_16x16x32_i8(a02, hq2, z4, 0,0,0);
    #pragma unroll
    for (int e = 0; e < 4; ++e) facc0[e] += (float)q[e]*s2;
    q = __builtin_amdgcn_mfma_i32_16x16x32_i8(a03, hq3, z4, 0,0,0);
    #pragma unroll
    for (int e = 0; e < 4; ++e) facc0[e] += (float)q[e]*s3;
    q = __builtin_amdgcn_mfma_i32_16x16x32_i8(a10, hq0, z4, 0,0,0);
    #pragma unroll
    for (int e = 0; e < 4; ++e) facc1[e] += (float)q[e]*s0;
    q = __builtin_amdgcn_mfma_i32_16x16x32_i8(a11, hq1, z4, 0,0,0);
    #pragma unroll
    for (int e = 0; e < 4; ++e) facc1[e] += (float)q[e]*s1;
    q = __builtin_amdgcn_mfma_i32_16x16x32_i8(a12, hq2, z4, 0,0,0);
    #pragma unroll
    for (int e = 0; e < 4; ++e) facc1[e] += (float)q[e]*s2;
    q = __builtin_amdgcn_mfma_i32_16x16x32_i8(a13, hq3, z4, 0,0,0);
    #pragma unroll
    for (int e = 0; e < 4; ++e) facc1[e] += (float)q[e]*s3;
    q = __builtin_amdgcn_mfma_i32_16x16x32_i8(haq0, qg0, z4, 0,0,0);
    #pragma unroll
    for (int e = 0; e < 4; ++e) aghf[e] += (float)q[e]*g0;
    q = __builtin_amdgcn_mfma_i32_16x16x32_i8(haq1, qg1, z4, 0,0,0);
    #pragma unroll
    for (int e = 0; e < 4; ++e) aghf[e] += (float)q[e]*g1;
  };

  __syncthreads();
  ISSUE(bufA, 0); ISSUE(bufB, 1);   // prologue: 2 chunks in flight
  for (int t = 0; t < 128; ++t) {
    int rb = t & 1;
    if (t > 0 && tid == 0) {
      while (__hip_atomic_load(&bar[(g<<7)+(t-1)], __ATOMIC_ACQUIRE, __HIP_MEMORY_SCOPE_AGENT) < 32u)
        __builtin_amdgcn_s_sleep(1);
    }
    __builtin_amdgcn_s_barrier();
    { // stage h: wave w stages its sample (2 KB)
      const char* hs = (const char*)(h_buf + (size_t)rb*B_*HD_ + (size_t)(gs + w)*HD_) + lane*16;
      glds16(hs,        &h_bf[w*1048]);
      glds16(hs + 1024, &h_bf[w*1048 + 512]);
    }
    if (tid < 256) x_lds[tid] = inputs[((size_t)sg_t*T_ + t)*DIN_ + c_t];
    asm volatile("s_waitcnt vmcnt(0)" ::: "memory");   // own h glds + x + prefetch landed
    { // quantize OWN staged row (no cross-wave dep -> no barrier needed yet)
      i32x4 pk;
      #pragma unroll
      for (int hh = 0; hh < 2; ++hh) {
        bf16x8 hv = *(const bf16x8*)(&h_bf[w*1048 + lane*16 + hh*8]);
        int lo = 0, hi2 = 0;
        #pragma unroll
        for (int e = 0; e < 4; ++e) {
          int q = (int)rintf(b2f((unsigned short)hv[e]) * 127.f);
          lo |= (q & 255) << (8*e);
        }
        #pragma unroll
        for (int e = 0; e < 4; ++e) {
          int q = (int)rintf(b2f((unsigned short)hv[4+e]) * 127.f);
          hi2 |= (q & 255) << (8*e);
        }
        pk[2*hh] = lo; pk[2*hh+1] = hi2;
      }
      *(i32x4*)(h_q8 + w*1040 + lane*16) = pk;
    }
    asm volatile("s_waitcnt lgkmcnt(0)" ::: "memory");
    __builtin_amdgcn_s_barrier();   // single barrier publishes h_bf + h_q8 (all rows)
    aghf = (f32x4){0,0,0,0}; facc0 = (f32x4){0,0,0,0}; facc1 = (f32x4){0,0,0,0};
    #pragma unroll 1
    for (int i2 = 0; i2 < 4; ++i2) {   // 8 chunks; HALF 6,7 wrap-issue next step
      HALF(bufA, 2*i2);
      HALF(bufB, 2*i2 + 1);
    }
    // exchange partials
    if (lane < 32) {          // gh D rows 0..7 = samples, cols = lane&15
      #pragma unroll
      for (int i = 0; i < 4; ++i)
        gh_lds[w*128 + ((lane>>4)*4 + i)*16 + (lane&15)] = aghf[i];
    }
    if ((lane & 15) == 0) {   // mv valid at n=0; rows = col-in-tile
      int cb = (lane>>4)*4;
      #pragma unroll
      for (int i = 0; i < 4; ++i) {
        mv_lds[w*32 + cb + i]      = facc0[i];
        mv_lds[w*32 + 16 + cb + i] = facc1[i];
      }
    }
    asm volatile("s_waitcnt lgkmcnt(0)" ::: "memory");
    __builtin_amdgcn_s_barrier();
    if (tid < 256) {
      int jr = c_t >> 4, cl16 = c_t & 15;
      float ghr = gh_lds[(2*jr)*128   + s_t*16 + cl16] + gh_lds[(2*jr+1)*128 + s_t*16 + cl16];
      float ghz = gh_lds[(4+2*jr)*128 + s_t*16 + cl16] + gh_lds[(5+2*jr)*128 + s_t*16 + cl16];
      float gxr = 0.f, gxz = 0.f, ex = 0.f;
      #pragma unroll 8
      for (int i = 0; i < 32; ++i) {
        float xv = x_lds[s_t*32 + i];
        gxr += xv * b2f(gwih_lds[i*64 + c_t]);
        gxz += xv * b2f(gwih_lds[i*64 + 32 + c_t]);
        ex  += xv * b2f(wih_lds[s_t*1024 + i*32 + c_t]);
      }
      float r = sigm_(gxr + ghr + br_b);
      float z = sigm_(gxz + ghz + bz_b);
      float eta = tanh_(ex + bh_r + r * mv_lds[s_t*32 + c_t]);
      float ho_ = b2f(h_bf[s_t*1048 + c0 + c_t]);
      float hn = z*ho_ + (1.f - z)*eta;
      dec[((size_t)sg_t*T_ + t)*HD_ + cg_t] = hn;
      h_buf[(size_t)(rb^1)*B_*HD_ + (size_t)sg_t*HD_ + cg_t] = f2b(hn);
      if (t == 127) out_states[(size_t)sg_t*HD_ + cg_t] = hn;
    }
    asm volatile("s_waitcnt vmcnt(0)" ::: "memory");  // stores (+wrap prefetch) drained
    __builtin_amdgcn_s_barrier();
    if (t < 127 && tid == 0)
      __hip_atomic_fetch_add(&bar[(g<<7)+t], 1u, __ATOMIC_ACQ_REL, __HIP_MEMORY_SCOPE_AGENT);
  }
}

// ---------------- yhats = dec @ C_b + concat(x, x @ D_b) ----------------
__global__ __launch_bounds__(256) void k_yhats(
    const float* __restrict__ dec, const float* __restrict__ inputs,
    const float* __restrict__ params, float* __restrict__ out_y)
{
  __shared__ __align__(16) float dsm[8*1024];
  __shared__ float xr[8*32];
  int blk = blockIdx.x, tid = threadIdx.x;
  int b = blk >> 4, t8 = (blk & 15) * 8;
  const float* prm = params + (size_t)b*PPS_;
  const float* C = prm + 33792;
  const float* D = prm + 99328;
  #pragma unroll
  for (int j = 0; j < 8; ++j) {
    int ch = j*256 + tid;
    *(f32x4*)(&dsm[ch*4]) = *(const f32x4*)(dec + ((size_t)b*T_ + t8)*HD_ + ch*4);
  }
  {
    int tl = tid >> 5, i = tid & 31;
    xr[tl*32 + i] = inputs[((size_t)b*T_ + t8 + tl)*DIN_ + i];
    xr[(tl+4)*32 + i] = inputs[((size_t)b*T_ + t8 + tl + 4)*DIN_ + i];
  }
  __syncthreads();
  int o = tid & 63;
  int tl0 = (tid >> 6) * 2;
  float a0 = 0.f, a1 = 0.f;
  #pragma unroll 4
  for (int h = 0; h < 1024; ++h) {
    float cv = C[h*64 + o];
    a0 += dsm[tl0*1024 + h] * cv;
    a1 += dsm[(tl0+1)*1024 + h] * cv;
  }
  float r0, r1;
  if (o < 32) {
    r0 = xr[tl0*32 + o];
    r1 = xr[(tl0+1)*32 + o];
  } else {
    r0 = 0.f; r1 = 0.f;
    #pragma unroll 8
    for (int i = 0; i < 32; ++i) {
      float dv = D[i*32 + (o-32)];
      r0 += xr[tl0*32 + i] * dv;
      r1 += xr[(tl0+1)*32 + i] * dv;
    }
  }
  out_y[((size_t)b*T_ + t8 + tl0)*DOUT_ + o]     = a0 + r0;
  out_y[((size_t)b*T_ + t8 + tl0 + 1)*DOUT_ + o] = a1 + r1;
}

extern "C" void kernel_launch(void* const* d_in, const int* in_sizes, int n_in,
                              void* d_out, int out_size, void* d_ws, size_t ws_size,
                              hipStream_t stream)
{
  const float* inputs  = (const float*)d_in[0];
  const float* outputs = (const float*)d_in[1];
  const float* eps     = (const float*)d_in[2];
  const float* state   = (const float*)d_in[3];
  const float* enc_Wih = (const float*)d_in[4];
  const float* enc_Whh = (const float*)d_in[5];
  const float* enc_bih = (const float*)d_in[6];
  const float* enc_bhh = (const float*)d_in[7];
  const float* to_mu   = (const float*)d_in[8];
  const float* to_ls   = (const float*)d_in[9];
  const float* to_lsb  = (const float*)d_in[10];
  const float* psi_W1  = (const float*)d_in[11];
  const float* psi_b1  = (const float*)d_in[12];
  const float* psi_W2  = (const float*)d_in[13];
  const float* psi_b2  = (const float*)d_in[14];
  const float* psi_W3  = (const float*)d_in[15];
  const float* psi_b3  = (const float*)d_in[16];
  const float* gru_Wih = (const float*)d_in[17];
  const float* gru_Whh = (const float*)d_in[18];
  const float* gru_bias= (const float*)d_in[19];
  float* out    = (float*)d_out;
  float* out_y  = out;
  float* out_mu = out + 524288;
  float* out_ls = out + 525056;
  float* out_st = out + 525824;

  if (ws_size < 130000000) return;  // fail loudly rather than corrupt
  char* ws = (char*)d_ws;
  size_t off = 0;
  auto alloc = [&](size_t bytes)->char*{ char* p = ws + off; off += (bytes + 255) & ~(size_t)255; return p; };
  signed char* whh_q      = (signed char*)alloc(67108864);
  float* scales           = (float*)alloc(262144);
  unsigned short* encW_f  = (unsigned short*)alloc(1572864);
  unsigned short* encI_f  = (unsigned short*)alloc(196608);
  signed char* gru_q      = (signed char*)alloc(2097152);
  float* scales_g         = (float*)alloc(16384);
  float* params           = (float*)alloc(25690112);
  float* h_enc            = (float*)alloc(131072);
  float* z_lat            = (float*)alloc(3072);
  float* hidden_T         = (float*)alloc(16384);
  unsigned short* h_buf_e = (unsigned short*)alloc(131072);
  unsigned short* h_buf_d = (unsigned short*)alloc(262144);
  float* dec              = (float*)alloc(33554432);
  unsigned int* bar_e     = (unsigned int*)alloc(8192);
  unsigned int* bar_d     = (unsigned int*)alloc(8192);

  hipMemsetAsync(bar_e, 0, 8192, stream);
  hipMemsetAsync(bar_d, 0, 8192, stream);
  hipMemsetAsync(h_buf_e, 0, 131072, stream);

  k_prep<<<5888, 512, 0, stream>>>(enc_Whh, enc_Wih, gru_Whh, state, encW_f, encI_f, gru_q, scales_g, h_buf_d);
  k_encoder<<<256, 128, 0, stream>>>(outputs, enc_bih, enc_bhh, encW_f, encI_f, h_buf_e, h_enc, bar_e);
  k_latent<<<64, 64, 0, stream>>>(h_enc, to_mu, to_ls, to_lsb, eps, out_mu, out_ls, z_lat);
  k_hidden<<<64, 512, 0, stream>>>(z_lat, psi_W1, psi_b1, psi_W2, psi_b2, hidden_T);
  k_psi<<<2146, 1024, 0, stream>>>(hidden_T, psi_W3, psi_b3, whh_q, scales, params);
  k_decoder<<<256, 512, 0, stream>>>(inputs, gru_Wih, gru_bias, whh_q, scales, gru_q, scales_g, params, h_buf_d, dec, out_st, bar_d);
  k_yhats<<<1024, 256, 0, stream>>>(dec, inputs, params, out_y);
}